// Round 1
// baseline (1094.252 us; speedup 1.0000x reference)
//
#include <hip/hip_runtime.h>
#include <hip/hip_bf16.h>
#include <math.h>

// ---------------- problem constants (derived defensively in kernel_launch) ---
// N_NODES=100000, N_EDGES=1000000, IN_CH=64, HID=128, OUT_CH=2, N_GRAPHS=256

// ---------------- CSR build ---------------------------------------------------

__global__ void k_count_deg(const int* __restrict__ dst, int* __restrict__ deg, int E) {
    int e = blockIdx.x * blockDim.x + threadIdx.x;
    if (e < E) atomicAdd(&deg[dst[e]], 1);
}

// single-block exclusive scan over n elements (n ~ 100k). 1024 threads.
__global__ void k_scan(const int* __restrict__ deg, int* __restrict__ row_start, int n) {
    __shared__ int sums[1024];
    int tid = threadIdx.x;
    int per = (n + 1023) / 1024;
    int start = tid * per;
    int end   = start + per; if (end > n) end = n;
    int s = 0;
    for (int i = start; i < end; ++i) s += deg[i];
    sums[tid] = s;
    __syncthreads();
    for (int off = 1; off < 1024; off <<= 1) {
        int v = (tid >= off) ? sums[tid - off] : 0;
        __syncthreads();
        sums[tid] += v;
        __syncthreads();
    }
    int prefix = (tid == 0) ? 0 : sums[tid - 1];
    int run = prefix;
    for (int i = start; i < end; ++i) { row_start[i] = run; run += deg[i]; }
    if (tid == 1023) row_start[n] = run;
}

__global__ void k_scatter(const int* __restrict__ src, const int* __restrict__ dst,
                          const int* __restrict__ row_start, int* __restrict__ cursor,
                          int* __restrict__ csr_src, int E) {
    int e = blockIdx.x * blockDim.x + threadIdx.x;
    if (e >= E) return;
    int d = dst[e];
    int pos = atomicAdd(&cursor[d], 1);
    csr_src[row_start[d] + pos] = src[e];
}

// ---------------- mean aggregation via CSR gather ----------------------------
// 64 lanes per node; K=64: 1 float/lane, K=128: float2/lane.

template <int K>
__global__ void k_gather_mean(const float* __restrict__ feat,
                              const int* __restrict__ row_start,
                              const int* __restrict__ deg,
                              const int* __restrict__ csr_src,
                              float* __restrict__ out, int n_nodes) {
    int lane = threadIdx.x & 63;
    int grp  = threadIdx.x >> 6;           // 4 nodes per 256-thread block
    int node = blockIdx.x * 4 + grp;
    if (node >= n_nodes) return;
    int s = row_start[node];
    int d = deg[node];
    int e = s + d;
    if (K == 64) {
        float acc = 0.f;
        for (int i = s; i < e; ++i) {
            int u = csr_src[i];
            acc += feat[(size_t)u * 64 + lane];
        }
        float scale = (d > 0) ? (1.f / (float)d) : 1.f;
        out[(size_t)node * 64 + lane] = acc * scale;
    } else {
        float a0 = 0.f, a1 = 0.f;
        for (int i = s; i < e; ++i) {
            int u = csr_src[i];
            float2 v = ((const float2*)(feat + (size_t)u * 128))[lane];
            a0 += v.x; a1 += v.y;
        }
        float scale = (d > 0) ? (1.f / (float)d) : 1.f;
        float2 o; o.x = a0 * scale; o.y = a1 * scale;
        ((float2*)(out + (size_t)node * 128))[lane] = o;
    }
}

// ---------------- fused SAGE linear: out = relu(agg@Wl.T + bl + xin@Wr.T) ----
// Tile: 64 nodes x 128 outputs, 256 threads, each thread 4 nodes x 8 j.
// Virtual reduce dim 2K: first K cols from (agg,Wl), next K from (xin,Wr).

template <int K>
__global__ __launch_bounds__(256) void k_linear(
    const float* __restrict__ agg, const float* __restrict__ xin,
    const float* __restrict__ Wl,  const float* __restrict__ bl,
    const float* __restrict__ Wr,  float* __restrict__ out, int n_nodes) {
    constexpr int TK = 2 * K;
    constexpr int CH = 32;
    __shared__ __align__(16) float As[64][36];   // 64 nodes x 32 k (pad 36)
    __shared__ __align__(16) float Bs[CH][128];  // 32 k x 128 j (k-major)

    int tid   = threadIdx.x;
    int nslot = tid & 15;      // node slot: nodes nslot + i*16
    int jslot = tid >> 4;      // j slot: j = jslot*8 + q
    int jbase = jslot * 8;
    int node0 = blockIdx.x * 64;

    float acc[4][8];
#pragma unroll
    for (int i = 0; i < 4; ++i)
#pragma unroll
        for (int q = 0; q < 8; ++q) acc[i][q] = 0.f;

    for (int ch = 0; ch < TK / CH; ++ch) {
        const float* srcA;
        const float* srcW;
        int kbase;
        if (ch * CH < K) { srcA = agg; srcW = Wl; kbase = ch * CH; }
        else             { srcA = xin; srcW = Wr; kbase = ch * CH - K; }

        // stage A: 64 rows x 32 cols
        {
            int slot = tid & 7;     // float4 slot within 32 cols
            int row  = tid >> 3;    // 0..31
#pragma unroll
            for (int h = 0; h < 2; ++h) {
                int r = row + 32 * h;
                int n = node0 + r;
                float4 v = make_float4(0.f, 0.f, 0.f, 0.f);
                if (n < n_nodes)
                    v = *(const float4*)(srcA + (size_t)n * K + kbase + slot * 4);
                *(float4*)(&As[r][slot * 4]) = v;
            }
        }
        // stage B (transpose W[j][k] -> Bs[k][j]): 32 k x 128 j
        {
            int kslot = tid & 7;
            int j0    = tid >> 3;   // 0..31
#pragma unroll
            for (int h = 0; h < 4; ++h) {
                int j = j0 + 32 * h;
                float4 w = *(const float4*)(srcW + (size_t)j * K + kbase + kslot * 4);
                Bs[kslot * 4 + 0][j] = w.x;
                Bs[kslot * 4 + 1][j] = w.y;
                Bs[kslot * 4 + 2][j] = w.z;
                Bs[kslot * 4 + 3][j] = w.w;
            }
        }
        __syncthreads();

#pragma unroll
        for (int k4 = 0; k4 < CH; k4 += 4) {
            float4 av[4];
#pragma unroll
            for (int i = 0; i < 4; ++i)
                av[i] = *(const float4*)(&As[nslot + i * 16][k4]);
#pragma unroll
            for (int kk = 0; kk < 4; ++kk) {
                float bq[8];
#pragma unroll
                for (int q = 0; q < 8; ++q) bq[q] = Bs[k4 + kk][jbase + q];
#pragma unroll
                for (int i = 0; i < 4; ++i) {
                    float a = ((const float*)&av[i])[kk];
#pragma unroll
                    for (int q = 0; q < 8; ++q)
                        acc[i][q] = fmaf(a, bq[q], acc[i][q]);
                }
            }
        }
        __syncthreads();
    }

    // epilogue: bias + relu + store
    float bias[8];
#pragma unroll
    for (int q = 0; q < 8; ++q) bias[q] = bl[jbase + q];
#pragma unroll
    for (int i = 0; i < 4; ++i) {
        int n = node0 + nslot + i * 16;
        if (n < n_nodes) {
            float4 o0, o1;
            o0.x = fmaxf(acc[i][0] + bias[0], 0.f);
            o0.y = fmaxf(acc[i][1] + bias[1], 0.f);
            o0.z = fmaxf(acc[i][2] + bias[2], 0.f);
            o0.w = fmaxf(acc[i][3] + bias[3], 0.f);
            o1.x = fmaxf(acc[i][4] + bias[4], 0.f);
            o1.y = fmaxf(acc[i][5] + bias[5], 0.f);
            o1.z = fmaxf(acc[i][6] + bias[6], 0.f);
            o1.w = fmaxf(acc[i][7] + bias[7], 0.f);
            *(float4*)(out + (size_t)n * 128 + jbase)     = o0;
            *(float4*)(out + (size_t)n * 128 + jbase + 4) = o1;
        }
    }
}

// ---------------- pooling ----------------------------------------------------

__global__ void k_pool(const float* __restrict__ h2, const int* __restrict__ batch,
                       float* __restrict__ pooled, float* __restrict__ cnt, int n_nodes) {
    int idx = blockIdx.x * blockDim.x + threadIdx.x;
    int total = n_nodes * 128;
    if (idx >= total) return;
    int n = idx >> 7;
    int c = idx & 127;
    int g = batch[n];
    atomicAdd(&pooled[g * 128 + c], h2[idx]);
    if (c == 0) atomicAdd(&cnt[g], 1.0f);
}

// ---------------- head: mean, linear [2x128], log_softmax -------------------

__global__ void k_head(const float* __restrict__ pooled, const float* __restrict__ cnt,
                       const float* __restrict__ Wout, const float* __restrict__ bout,
                       float* __restrict__ out) {
    int g = blockIdx.x;
    int lane = threadIdx.x;  // 64 lanes, 2 channels each
    float c = cnt[g];
    float inv = (c > 0.f) ? (1.f / c) : 1.f;
    float2 p  = ((const float2*)(pooled + g * 128))[lane];
    p.x *= inv; p.y *= inv;
    float2 w0 = ((const float2*)(Wout))[lane];
    float2 w1 = ((const float2*)(Wout + 128))[lane];
    float d0 = p.x * w0.x + p.y * w0.y;
    float d1 = p.x * w1.x + p.y * w1.y;
#pragma unroll
    for (int m = 32; m > 0; m >>= 1) {
        d0 += __shfl_xor(d0, m);
        d1 += __shfl_xor(d1, m);
    }
    if (lane == 0) {
        float l0 = d0 + bout[0];
        float l1 = d1 + bout[1];
        float mx = fmaxf(l0, l1);
        float lse = mx + logf(expf(l0 - mx) + expf(l1 - mx));
        out[g * 2 + 0] = l0 - lse;
        out[g * 2 + 1] = l1 - lse;
    }
}

// ---------------- launch -----------------------------------------------------

static inline size_t alignUp(size_t x, size_t a) { return (x + a - 1) & ~(a - 1); }

extern "C" void kernel_launch(void* const* d_in, const int* in_sizes, int n_in,
                              void* d_out, int out_size, void* d_ws, size_t ws_size,
                              hipStream_t stream) {
    const float* x    = (const float*)d_in[0];
    const int*   ei   = (const int*)d_in[1];
    const int*   batch= (const int*)d_in[2];
    const float* Wl1  = (const float*)d_in[3];
    const float* bl1  = (const float*)d_in[4];
    const float* Wr1  = (const float*)d_in[5];
    const float* Wl2  = (const float*)d_in[6];
    const float* bl2  = (const float*)d_in[7];
    const float* Wr2  = (const float*)d_in[8];
    const float* Wout = (const float*)d_in[9];
    const float* bout = (const float*)d_in[10];
    float* out = (float*)d_out;

    const int N = in_sizes[0] / 64;   // 100000
    const int E = in_sizes[1] / 2;    // 1000000
    const int G = out_size / 2;       // 256

    const int* src = ei;
    const int* dst = ei + E;

    // workspace layout
    char* ws = (char*)d_ws;
    size_t off = 0;
    int*   deg       = (int*)(ws + off); off = alignUp(off + (size_t)N * 4, 256);
    int*   row_start = (int*)(ws + off); off = alignUp(off + (size_t)(N + 1) * 4, 256);
    int*   cursor    = (int*)(ws + off); off = alignUp(off + (size_t)N * 4, 256);
    int*   csr_src   = (int*)(ws + off); off = alignUp(off + (size_t)E * 4, 256);
    float* agg       = (float*)(ws + off); off = alignUp(off + (size_t)N * 128 * 4, 256);
    float* h1        = (float*)(ws + off); off = alignUp(off + (size_t)N * 128 * 4, 256);
    float* pooled    = (float*)(ws + off); size_t pooled_off = off; off = alignUp(off + (size_t)G * 128 * 4, 256);
    float* cnt       = (float*)(ws + off); off = alignUp(off + (size_t)G * 4, 256);
    size_t end_off = off;
    (void)ws_size;

    // zero: deg..cursor (contiguous region), pooled..cnt (contiguous region)
    hipMemsetAsync(deg, 0, (char*)csr_src - (char*)deg, stream);
    hipMemsetAsync(pooled, 0, end_off - pooled_off, stream);

    // CSR build
    k_count_deg<<<(E + 255) / 256, 256, 0, stream>>>(dst, deg, E);
    k_scan<<<1, 1024, 0, stream>>>(deg, row_start, N);
    k_scatter<<<(E + 255) / 256, 256, 0, stream>>>(src, dst, row_start, cursor, csr_src, E);

    // layer 1: agg(K=64) -> h1 = relu(agg@Wl1.T + bl1 + x@Wr1.T)
    k_gather_mean<64><<<(N + 3) / 4, 256, 0, stream>>>(x, row_start, deg, csr_src, agg, N);
    k_linear<64><<<(N + 63) / 64, 256, 0, stream>>>(agg, x, Wl1, bl1, Wr1, h1, N);

    // layer 2: agg2(K=128 from h1) -> h2 = relu(agg2@Wl2.T + bl2 + h1@Wr2.T)
    // h2 written in-place over agg (each block stores only its own rows, after reads)
    k_gather_mean<128><<<(N + 3) / 4, 256, 0, stream>>>(h1, row_start, deg, csr_src, agg, N);
    k_linear<128><<<(N + 63) / 64, 256, 0, stream>>>(agg, h1, Wl2, bl2, Wr2, agg, N);

    // pool + head
    k_pool<<<((size_t)N * 128 + 255) / 256, 256, 0, stream>>>(agg, batch, pooled, cnt, N);
    k_head<<<G, 64, 0, stream>>>(pooled, cnt, Wout, bout, out);
}

// Round 2
// 749.172 us; speedup vs baseline: 1.4606x; 1.4606x over previous
//
#include <hip/hip_runtime.h>
#include <hip/hip_bf16.h>
#include <math.h>

// ---------------- problem constants (derived defensively in kernel_launch) ---
// N_NODES=100000, N_EDGES=1000000, IN_CH=64, HID=128, OUT_CH=2, N_GRAPHS=256

// ---------------- CSR build ---------------------------------------------------

__global__ void k_count_deg(const int* __restrict__ dst, int* __restrict__ deg, int E) {
    int e = blockIdx.x * blockDim.x + threadIdx.x;
    if (e < E) atomicAdd(&deg[dst[e]], 1);
}

// single-block exclusive scan over n elements (n ~ 100k). 1024 threads.
__global__ void k_scan(const int* __restrict__ deg, int* __restrict__ row_start, int n) {
    __shared__ int sums[1024];
    int tid = threadIdx.x;
    int per = (n + 1023) / 1024;
    int start = tid * per;
    int end   = start + per; if (end > n) end = n;
    int s = 0;
    for (int i = start; i < end; ++i) s += deg[i];
    sums[tid] = s;
    __syncthreads();
    for (int off = 1; off < 1024; off <<= 1) {
        int v = (tid >= off) ? sums[tid - off] : 0;
        __syncthreads();
        sums[tid] += v;
        __syncthreads();
    }
    int prefix = (tid == 0) ? 0 : sums[tid - 1];
    int run = prefix;
    for (int i = start; i < end; ++i) { row_start[i] = run; run += deg[i]; }
    if (tid == 1023) row_start[n] = run;
}

__global__ void k_scatter(const int* __restrict__ src, const int* __restrict__ dst,
                          const int* __restrict__ row_start, int* __restrict__ cursor,
                          int* __restrict__ csr_src, int E) {
    int e = blockIdx.x * blockDim.x + threadIdx.x;
    if (e >= E) return;
    int d = dst[e];
    int pos = atomicAdd(&cursor[d], 1);
    csr_src[row_start[d] + pos] = src[e];
}

// ---------------- mean aggregation via CSR gather ----------------------------
// 64 lanes per node; K=64: 1 float/lane, K=128: float2/lane.

template <int K>
__global__ void k_gather_mean(const float* __restrict__ feat,
                              const int* __restrict__ row_start,
                              const int* __restrict__ deg,
                              const int* __restrict__ csr_src,
                              float* __restrict__ out, int n_nodes) {
    int lane = threadIdx.x & 63;
    int grp  = threadIdx.x >> 6;           // 4 nodes per 256-thread block
    int node = blockIdx.x * 4 + grp;
    if (node >= n_nodes) return;
    int s = row_start[node];
    int d = deg[node];
    int e = s + d;
    if (K == 64) {
        float acc = 0.f;
        for (int i = s; i < e; ++i) {
            int u = csr_src[i];
            acc += feat[(size_t)u * 64 + lane];
        }
        float scale = (d > 0) ? (1.f / (float)d) : 1.f;
        out[(size_t)node * 64 + lane] = acc * scale;
    } else {
        float a0 = 0.f, a1 = 0.f;
        for (int i = s; i < e; ++i) {
            int u = csr_src[i];
            float2 v = ((const float2*)(feat + (size_t)u * 128))[lane];
            a0 += v.x; a1 += v.y;
        }
        float scale = (d > 0) ? (1.f / (float)d) : 1.f;
        float2 o; o.x = a0 * scale; o.y = a1 * scale;
        ((float2*)(out + (size_t)node * 128))[lane] = o;
    }
}

// ---------------- fused SAGE linear: out = relu(agg@Wl.T + bl + xin@Wr.T) ----
// Tile: 64 nodes x 128 outputs, 256 threads, each thread 4 nodes x 8 j.
// Virtual reduce dim 2K: first K cols from (agg,Wl), next K from (xin,Wr).

template <int K>
__global__ __launch_bounds__(256) void k_linear(
    const float* __restrict__ agg, const float* __restrict__ xin,
    const float* __restrict__ Wl,  const float* __restrict__ bl,
    const float* __restrict__ Wr,  float* __restrict__ out, int n_nodes) {
    constexpr int TK = 2 * K;
    constexpr int CH = 32;
    __shared__ __align__(16) float As[64][36];   // 64 nodes x 32 k (pad 36)
    __shared__ __align__(16) float Bs[CH][128];  // 32 k x 128 j (k-major)

    int tid   = threadIdx.x;
    int nslot = tid & 15;      // node slot: nodes nslot + i*16
    int jslot = tid >> 4;      // j slot: j = jslot*8 + q
    int jbase = jslot * 8;
    int node0 = blockIdx.x * 64;

    float acc[4][8];
#pragma unroll
    for (int i = 0; i < 4; ++i)
#pragma unroll
        for (int q = 0; q < 8; ++q) acc[i][q] = 0.f;

    for (int ch = 0; ch < TK / CH; ++ch) {
        const float* srcA;
        const float* srcW;
        int kbase;
        if (ch * CH < K) { srcA = agg; srcW = Wl; kbase = ch * CH; }
        else             { srcA = xin; srcW = Wr; kbase = ch * CH - K; }

        // stage A: 64 rows x 32 cols
        {
            int slot = tid & 7;     // float4 slot within 32 cols
            int row  = tid >> 3;    // 0..31
#pragma unroll
            for (int h = 0; h < 2; ++h) {
                int r = row + 32 * h;
                int n = node0 + r;
                float4 v = make_float4(0.f, 0.f, 0.f, 0.f);
                if (n < n_nodes)
                    v = *(const float4*)(srcA + (size_t)n * K + kbase + slot * 4);
                *(float4*)(&As[r][slot * 4]) = v;
            }
        }
        // stage B (transpose W[j][k] -> Bs[k][j]): 32 k x 128 j
        {
            int kslot = tid & 7;
            int j0    = tid >> 3;   // 0..31
#pragma unroll
            for (int h = 0; h < 4; ++h) {
                int j = j0 + 32 * h;
                float4 w = *(const float4*)(srcW + (size_t)j * K + kbase + kslot * 4);
                Bs[kslot * 4 + 0][j] = w.x;
                Bs[kslot * 4 + 1][j] = w.y;
                Bs[kslot * 4 + 2][j] = w.z;
                Bs[kslot * 4 + 3][j] = w.w;
            }
        }
        __syncthreads();

#pragma unroll
        for (int k4 = 0; k4 < CH; k4 += 4) {
            float4 av[4];
#pragma unroll
            for (int i = 0; i < 4; ++i)
                av[i] = *(const float4*)(&As[nslot + i * 16][k4]);
#pragma unroll
            for (int kk = 0; kk < 4; ++kk) {
                float bq[8];
#pragma unroll
                for (int q = 0; q < 8; ++q) bq[q] = Bs[k4 + kk][jbase + q];
#pragma unroll
                for (int i = 0; i < 4; ++i) {
                    float a = ((const float*)&av[i])[kk];
#pragma unroll
                    for (int q = 0; q < 8; ++q)
                        acc[i][q] = fmaf(a, bq[q], acc[i][q]);
                }
            }
        }
        __syncthreads();
    }

    // epilogue: bias + relu + store
    float bias[8];
#pragma unroll
    for (int q = 0; q < 8; ++q) bias[q] = bl[jbase + q];
#pragma unroll
    for (int i = 0; i < 4; ++i) {
        int n = node0 + nslot + i * 16;
        if (n < n_nodes) {
            float4 o0, o1;
            o0.x = fmaxf(acc[i][0] + bias[0], 0.f);
            o0.y = fmaxf(acc[i][1] + bias[1], 0.f);
            o0.z = fmaxf(acc[i][2] + bias[2], 0.f);
            o0.w = fmaxf(acc[i][3] + bias[3], 0.f);
            o1.x = fmaxf(acc[i][4] + bias[4], 0.f);
            o1.y = fmaxf(acc[i][5] + bias[5], 0.f);
            o1.z = fmaxf(acc[i][6] + bias[6], 0.f);
            o1.w = fmaxf(acc[i][7] + bias[7], 0.f);
            *(float4*)(out + (size_t)n * 128 + jbase)     = o0;
            *(float4*)(out + (size_t)n * 128 + jbase + 4) = o1;
        }
    }
}

// ---------------- pooling: batch is SORTED -> segmented reduction ------------

// gstart[g] = lower_bound(batch, g); gstart[G] = N. One thread per graph id.
__global__ void k_graph_bounds(const int* __restrict__ batch, int* __restrict__ gstart,
                               int N, int G) {
    int g = blockIdx.x * blockDim.x + threadIdx.x;
    if (g > G) return;
    if (g == G) { gstart[G] = N; return; }
    int lo = 0, hi = N;
    while (lo < hi) {
        int mid = (lo + hi) >> 1;
        if (batch[mid] < g) lo = mid + 1; else hi = mid;
    }
    gstart[g] = lo;
}

// one block per graph; 4 waves stride the graph's node range; lane = 2 channels
__global__ __launch_bounds__(256) void k_pool_seg(const float* __restrict__ h2,
                                                  const int* __restrict__ gstart,
                                                  float* __restrict__ pooled,
                                                  float* __restrict__ cnt) {
    int g = blockIdx.x;
    int s = gstart[g], e = gstart[g + 1];
    int lane = threadIdx.x & 63;
    int wave = threadIdx.x >> 6;
    float ax = 0.f, ay = 0.f;
    for (int n = s + wave; n < e; n += 4) {
        float2 v = ((const float2*)(h2 + (size_t)n * 128))[lane];
        ax += v.x; ay += v.y;
    }
    __shared__ float2 red[4][64];
    red[wave][lane] = make_float2(ax, ay);
    __syncthreads();
    if (wave == 0) {
        float2 a = red[0][lane], b = red[1][lane], c = red[2][lane], d = red[3][lane];
        float2 o;
        o.x = a.x + b.x + c.x + d.x;
        o.y = a.y + b.y + c.y + d.y;
        ((float2*)(pooled + g * 128))[lane] = o;
        if (lane == 0) cnt[g] = (float)(e - s);
    }
}

// ---------------- head: mean, linear [2x128], log_softmax -------------------

__global__ void k_head(const float* __restrict__ pooled, const float* __restrict__ cnt,
                       const float* __restrict__ Wout, const float* __restrict__ bout,
                       float* __restrict__ out) {
    int g = blockIdx.x;
    int lane = threadIdx.x;  // 64 lanes, 2 channels each
    float c = cnt[g];
    float inv = (c > 0.f) ? (1.f / c) : 1.f;
    float2 p  = ((const float2*)(pooled + g * 128))[lane];
    p.x *= inv; p.y *= inv;
    float2 w0 = ((const float2*)(Wout))[lane];
    float2 w1 = ((const float2*)(Wout + 128))[lane];
    float d0 = p.x * w0.x + p.y * w0.y;
    float d1 = p.x * w1.x + p.y * w1.y;
#pragma unroll
    for (int m = 32; m > 0; m >>= 1) {
        d0 += __shfl_xor(d0, m);
        d1 += __shfl_xor(d1, m);
    }
    if (lane == 0) {
        float l0 = d0 + bout[0];
        float l1 = d1 + bout[1];
        float mx = fmaxf(l0, l1);
        float lse = mx + logf(expf(l0 - mx) + expf(l1 - mx));
        out[g * 2 + 0] = l0 - lse;
        out[g * 2 + 1] = l1 - lse;
    }
}

// ---------------- launch -----------------------------------------------------

static inline size_t alignUp(size_t x, size_t a) { return (x + a - 1) & ~(a - 1); }

extern "C" void kernel_launch(void* const* d_in, const int* in_sizes, int n_in,
                              void* d_out, int out_size, void* d_ws, size_t ws_size,
                              hipStream_t stream) {
    const float* x    = (const float*)d_in[0];
    const int*   ei   = (const int*)d_in[1];
    const int*   batch= (const int*)d_in[2];
    const float* Wl1  = (const float*)d_in[3];
    const float* bl1  = (const float*)d_in[4];
    const float* Wr1  = (const float*)d_in[5];
    const float* Wl2  = (const float*)d_in[6];
    const float* bl2  = (const float*)d_in[7];
    const float* Wr2  = (const float*)d_in[8];
    const float* Wout = (const float*)d_in[9];
    const float* bout = (const float*)d_in[10];
    float* out = (float*)d_out;

    const int N = in_sizes[0] / 64;   // 100000
    const int E = in_sizes[1] / 2;    // 1000000
    const int G = out_size / 2;       // 256

    const int* src = ei;
    const int* dst = ei + E;

    // workspace layout
    char* ws = (char*)d_ws;
    size_t off = 0;
    int*   deg       = (int*)(ws + off); off = alignUp(off + (size_t)N * 4, 256);
    int*   row_start = (int*)(ws + off); off = alignUp(off + (size_t)(N + 1) * 4, 256);
    int*   cursor    = (int*)(ws + off); off = alignUp(off + (size_t)N * 4, 256);
    int*   csr_src   = (int*)(ws + off); off = alignUp(off + (size_t)E * 4, 256);
    int*   gstart    = (int*)(ws + off); off = alignUp(off + (size_t)(G + 1) * 4, 256);
    float* agg       = (float*)(ws + off); off = alignUp(off + (size_t)N * 128 * 4, 256);
    float* h1        = (float*)(ws + off); off = alignUp(off + (size_t)N * 128 * 4, 256);
    float* pooled    = (float*)(ws + off); off = alignUp(off + (size_t)G * 128 * 4, 256);
    float* cnt       = (float*)(ws + off); off = alignUp(off + (size_t)G * 4, 256);
    (void)ws_size;

    // zero deg/cursor region only (pooled/cnt are fully written by k_pool_seg)
    hipMemsetAsync(deg, 0, (char*)csr_src - (char*)deg, stream);

    // CSR build
    k_count_deg<<<(E + 255) / 256, 256, 0, stream>>>(dst, deg, E);
    k_scan<<<1, 1024, 0, stream>>>(deg, row_start, N);
    k_scatter<<<(E + 255) / 256, 256, 0, stream>>>(src, dst, row_start, cursor, csr_src, E);

    // graph segment bounds from sorted batch
    k_graph_bounds<<<2, 256, 0, stream>>>(batch, gstart, N, G);

    // layer 1: agg(K=64) -> h1 = relu(agg@Wl1.T + bl1 + x@Wr1.T)
    k_gather_mean<64><<<(N + 3) / 4, 256, 0, stream>>>(x, row_start, deg, csr_src, agg, N);
    k_linear<64><<<(N + 63) / 64, 256, 0, stream>>>(agg, x, Wl1, bl1, Wr1, h1, N);

    // layer 2: agg2(K=128 from h1) -> h2 = relu(agg2@Wl2.T + bl2 + h1@Wr2.T)
    // h2 written in-place over agg (each block stores only its own rows, after reads)
    k_gather_mean<128><<<(N + 3) / 4, 256, 0, stream>>>(h1, row_start, deg, csr_src, agg, N);
    k_linear<128><<<(N + 63) / 64, 256, 0, stream>>>(agg, h1, Wl2, bl2, Wr2, agg, N);

    // pool (segmented, no atomics) + head
    k_pool_seg<<<G, 256, 0, stream>>>(agg, gstart, pooled, cnt);
    k_head<<<G, 64, 0, stream>>>(pooled, cnt, Wout, bout, out);
}

// Round 3
// 594.874 us; speedup vs baseline: 1.8395x; 1.2594x over previous
//
#include <hip/hip_runtime.h>
#include <hip/hip_bf16.h>
#include <math.h>

// ---------------- problem constants (derived defensively in kernel_launch) ---
// N_NODES=100000, N_EDGES=1000000, IN_CH=64, HID=128, OUT_CH=2, N_GRAPHS=256

// ---------------- CSR build ---------------------------------------------------

__global__ void k_count_deg(const int* __restrict__ dst, int* __restrict__ deg, int E) {
    int e = blockIdx.x * blockDim.x + threadIdx.x;
    if (e < E) atomicAdd(&deg[dst[e]], 1);
}

// ---- multi-block exclusive scan over deg[0..n) -> row_start[0..n] -----------
// phase 1: per-block (256 elems) sum
__global__ void k_block_sum(const int* __restrict__ deg, int* __restrict__ bsum, int n) {
    __shared__ int red[256];
    int i = blockIdx.x * 256 + threadIdx.x;
    red[threadIdx.x] = (i < n) ? deg[i] : 0;
    __syncthreads();
#pragma unroll
    for (int off = 128; off > 0; off >>= 1) {
        if (threadIdx.x < off) red[threadIdx.x] += red[threadIdx.x + off];
        __syncthreads();
    }
    if (threadIdx.x == 0) bsum[blockIdx.x] = red[0];
}

// phase 2: single-block exclusive scan of nb (<=512) block sums, in place
__global__ void k_scan_bsum(int* __restrict__ bsum, int nb) {
    __shared__ int s[512];
    int t = threadIdx.x;
    int v = (t < nb) ? bsum[t] : 0;
    s[t] = v;
    __syncthreads();
#pragma unroll
    for (int off = 1; off < 512; off <<= 1) {
        int u = (t >= off) ? s[t - off] : 0;
        __syncthreads();
        s[t] += u;
        __syncthreads();
    }
    if (t < nb) bsum[t] = s[t] - v;   // exclusive
}

// phase 3: block-local exclusive scan + block prefix -> row_start (+ total)
__global__ void k_scan_final(const int* __restrict__ deg, const int* __restrict__ bsum,
                             int* __restrict__ row_start, int n) {
    __shared__ int s[256];
    int i = blockIdx.x * 256 + threadIdx.x;
    int v = (i < n) ? deg[i] : 0;
    s[threadIdx.x] = v;
    __syncthreads();
#pragma unroll
    for (int off = 1; off < 256; off <<= 1) {
        int u = (threadIdx.x >= off) ? s[threadIdx.x - off] : 0;
        __syncthreads();
        s[threadIdx.x] += u;
        __syncthreads();
    }
    int excl = s[threadIdx.x] - v + bsum[blockIdx.x];
    if (i < n) row_start[i] = excl;
    if (i == n - 1) row_start[n] = excl + v;
}

__global__ void k_scatter(const int* __restrict__ src, const int* __restrict__ dst,
                          const int* __restrict__ row_start, int* __restrict__ cursor,
                          int* __restrict__ csr_src, int E) {
    int e = blockIdx.x * blockDim.x + threadIdx.x;
    if (e >= E) return;
    int d = dst[e];
    int pos = atomicAdd(&cursor[d], 1);
    csr_src[row_start[d] + pos] = src[e];
}

// ---------------- mean aggregation via CSR gather ----------------------------
// 64 lanes per node; K=64: 1 float/lane, K=128: float2/lane.

template <int K>
__global__ void k_gather_mean(const float* __restrict__ feat,
                              const int* __restrict__ row_start,
                              const int* __restrict__ deg,
                              const int* __restrict__ csr_src,
                              float* __restrict__ out, int n_nodes) {
    int lane = threadIdx.x & 63;
    int grp  = threadIdx.x >> 6;           // 4 nodes per 256-thread block
    int node = blockIdx.x * 4 + grp;
    if (node >= n_nodes) return;
    int s = row_start[node];
    int d = deg[node];
    int e = s + d;
    if (K == 64) {
        float acc = 0.f;
        for (int i = s; i < e; ++i) {
            int u = csr_src[i];
            acc += feat[(size_t)u * 64 + lane];
        }
        float scale = (d > 0) ? (1.f / (float)d) : 1.f;
        out[(size_t)node * 64 + lane] = acc * scale;
    } else {
        float a0 = 0.f, a1 = 0.f;
        for (int i = s; i < e; ++i) {
            int u = csr_src[i];
            float2 v = ((const float2*)(feat + (size_t)u * 128))[lane];
            a0 += v.x; a1 += v.y;
        }
        float scale = (d > 0) ? (1.f / (float)d) : 1.f;
        float2 o; o.x = a0 * scale; o.y = a1 * scale;
        ((float2*)(out + (size_t)node * 128))[lane] = o;
    }
}

// ---------------- fused SAGE linear: out = relu(agg@Wl.T + bl + xin@Wr.T) ----
// Tile: 64 nodes x 128 outputs, 256 threads, each thread 4 nodes x 8 j.
// Virtual reduce dim 2K: first K cols from (agg,Wl), next K from (xin,Wr).

template <int K>
__global__ __launch_bounds__(256) void k_linear(
    const float* __restrict__ agg, const float* __restrict__ xin,
    const float* __restrict__ Wl,  const float* __restrict__ bl,
    const float* __restrict__ Wr,  float* __restrict__ out, int n_nodes) {
    constexpr int TK = 2 * K;
    constexpr int CH = 32;
    __shared__ __align__(16) float As[64][36];   // 64 nodes x 32 k (pad 36)
    __shared__ __align__(16) float Bs[CH][128];  // 32 k x 128 j (k-major)

    int tid   = threadIdx.x;
    int nslot = tid & 15;      // node slot: nodes nslot + i*16
    int jslot = tid >> 4;      // j slot: j = jslot*8 + q
    int jbase = jslot * 8;
    int node0 = blockIdx.x * 64;

    float acc[4][8];
#pragma unroll
    for (int i = 0; i < 4; ++i)
#pragma unroll
        for (int q = 0; q < 8; ++q) acc[i][q] = 0.f;

    for (int ch = 0; ch < TK / CH; ++ch) {
        const float* srcA;
        const float* srcW;
        int kbase;
        if (ch * CH < K) { srcA = agg; srcW = Wl; kbase = ch * CH; }
        else             { srcA = xin; srcW = Wr; kbase = ch * CH - K; }

        // stage A: 64 rows x 32 cols
        {
            int slot = tid & 7;     // float4 slot within 32 cols
            int row  = tid >> 3;    // 0..31
#pragma unroll
            for (int h = 0; h < 2; ++h) {
                int r = row + 32 * h;
                int n = node0 + r;
                float4 v = make_float4(0.f, 0.f, 0.f, 0.f);
                if (n < n_nodes)
                    v = *(const float4*)(srcA + (size_t)n * K + kbase + slot * 4);
                *(float4*)(&As[r][slot * 4]) = v;
            }
        }
        // stage B (transpose W[j][k] -> Bs[k][j]): 32 k x 128 j
        {
            int kslot = tid & 7;
            int j0    = tid >> 3;   // 0..31
#pragma unroll
            for (int h = 0; h < 4; ++h) {
                int j = j0 + 32 * h;
                float4 w = *(const float4*)(srcW + (size_t)j * K + kbase + kslot * 4);
                Bs[kslot * 4 + 0][j] = w.x;
                Bs[kslot * 4 + 1][j] = w.y;
                Bs[kslot * 4 + 2][j] = w.z;
                Bs[kslot * 4 + 3][j] = w.w;
            }
        }
        __syncthreads();

#pragma unroll
        for (int k4 = 0; k4 < CH; k4 += 4) {
            float4 av[4];
#pragma unroll
            for (int i = 0; i < 4; ++i)
                av[i] = *(const float4*)(&As[nslot + i * 16][k4]);
#pragma unroll
            for (int kk = 0; kk < 4; ++kk) {
                float bq[8];
#pragma unroll
                for (int q = 0; q < 8; ++q) bq[q] = Bs[k4 + kk][jbase + q];
#pragma unroll
                for (int i = 0; i < 4; ++i) {
                    float a = ((const float*)&av[i])[kk];
#pragma unroll
                    for (int q = 0; q < 8; ++q)
                        acc[i][q] = fmaf(a, bq[q], acc[i][q]);
                }
            }
        }
        __syncthreads();
    }

    // epilogue: bias + relu + store
    float bias[8];
#pragma unroll
    for (int q = 0; q < 8; ++q) bias[q] = bl[jbase + q];
#pragma unroll
    for (int i = 0; i < 4; ++i) {
        int n = node0 + nslot + i * 16;
        if (n < n_nodes) {
            float4 o0, o1;
            o0.x = fmaxf(acc[i][0] + bias[0], 0.f);
            o0.y = fmaxf(acc[i][1] + bias[1], 0.f);
            o0.z = fmaxf(acc[i][2] + bias[2], 0.f);
            o0.w = fmaxf(acc[i][3] + bias[3], 0.f);
            o1.x = fmaxf(acc[i][4] + bias[4], 0.f);
            o1.y = fmaxf(acc[i][5] + bias[5], 0.f);
            o1.z = fmaxf(acc[i][6] + bias[6], 0.f);
            o1.w = fmaxf(acc[i][7] + bias[7], 0.f);
            *(float4*)(out + (size_t)n * 128 + jbase)     = o0;
            *(float4*)(out + (size_t)n * 128 + jbase + 4) = o1;
        }
    }
}

// ---------------- pooling: batch is SORTED -> segmented reduction ------------

// gstart[g] = lower_bound(batch, g); gstart[G] = N. One thread per graph id.
__global__ void k_graph_bounds(const int* __restrict__ batch, int* __restrict__ gstart,
                               int N, int G) {
    int g = blockIdx.x * blockDim.x + threadIdx.x;
    if (g > G) return;
    if (g == G) { gstart[G] = N; return; }
    int lo = 0, hi = N;
    while (lo < hi) {
        int mid = (lo + hi) >> 1;
        if (batch[mid] < g) lo = mid + 1; else hi = mid;
    }
    gstart[g] = lo;
}

// one block per graph; 4 waves stride the graph's node range; lane = 2 channels
__global__ __launch_bounds__(256) void k_pool_seg(const float* __restrict__ h2,
                                                  const int* __restrict__ gstart,
                                                  float* __restrict__ pooled,
                                                  float* __restrict__ cnt) {
    int g = blockIdx.x;
    int s = gstart[g], e = gstart[g + 1];
    int lane = threadIdx.x & 63;
    int wave = threadIdx.x >> 6;
    float ax = 0.f, ay = 0.f;
    for (int n = s + wave; n < e; n += 4) {
        float2 v = ((const float2*)(h2 + (size_t)n * 128))[lane];
        ax += v.x; ay += v.y;
    }
    __shared__ float2 red[4][64];
    red[wave][lane] = make_float2(ax, ay);
    __syncthreads();
    if (wave == 0) {
        float2 a = red[0][lane], b = red[1][lane], c = red[2][lane], d = red[3][lane];
        float2 o;
        o.x = a.x + b.x + c.x + d.x;
        o.y = a.y + b.y + c.y + d.y;
        ((float2*)(pooled + g * 128))[lane] = o;
        if (lane == 0) cnt[g] = (float)(e - s);
    }
}

// ---------------- head: mean, linear [2x128], log_softmax -------------------

__global__ void k_head(const float* __restrict__ pooled, const float* __restrict__ cnt,
                       const float* __restrict__ Wout, const float* __restrict__ bout,
                       float* __restrict__ out) {
    int g = blockIdx.x;
    int lane = threadIdx.x;  // 64 lanes, 2 channels each
    float c = cnt[g];
    float inv = (c > 0.f) ? (1.f / c) : 1.f;
    float2 p  = ((const float2*)(pooled + g * 128))[lane];
    p.x *= inv; p.y *= inv;
    float2 w0 = ((const float2*)(Wout))[lane];
    float2 w1 = ((const float2*)(Wout + 128))[lane];
    float d0 = p.x * w0.x + p.y * w0.y;
    float d1 = p.x * w1.x + p.y * w1.y;
#pragma unroll
    for (int m = 32; m > 0; m >>= 1) {
        d0 += __shfl_xor(d0, m);
        d1 += __shfl_xor(d1, m);
    }
    if (lane == 0) {
        float l0 = d0 + bout[0];
        float l1 = d1 + bout[1];
        float mx = fmaxf(l0, l1);
        float lse = mx + logf(expf(l0 - mx) + expf(l1 - mx));
        out[g * 2 + 0] = l0 - lse;
        out[g * 2 + 1] = l1 - lse;
    }
}

// ---------------- launch -----------------------------------------------------

static inline size_t alignUp(size_t x, size_t a) { return (x + a - 1) & ~(a - 1); }

extern "C" void kernel_launch(void* const* d_in, const int* in_sizes, int n_in,
                              void* d_out, int out_size, void* d_ws, size_t ws_size,
                              hipStream_t stream) {
    const float* x    = (const float*)d_in[0];
    const int*   ei   = (const int*)d_in[1];
    const int*   batch= (const int*)d_in[2];
    const float* Wl1  = (const float*)d_in[3];
    const float* bl1  = (const float*)d_in[4];
    const float* Wr1  = (const float*)d_in[5];
    const float* Wl2  = (const float*)d_in[6];
    const float* bl2  = (const float*)d_in[7];
    const float* Wr2  = (const float*)d_in[8];
    const float* Wout = (const float*)d_in[9];
    const float* bout = (const float*)d_in[10];
    float* out = (float*)d_out;

    const int N = in_sizes[0] / 64;   // 100000
    const int E = in_sizes[1] / 2;    // 1000000
    const int G = out_size / 2;       // 256

    const int* src = ei;
    const int* dst = ei + E;

    const int nScanBlocks = (N + 255) / 256;   // 391 for N=100000 (<=512)

    // workspace layout
    char* ws = (char*)d_ws;
    size_t off = 0;
    int*   deg       = (int*)(ws + off); off = alignUp(off + (size_t)N * 4, 256);
    int*   row_start = (int*)(ws + off); off = alignUp(off + (size_t)(N + 1) * 4, 256);
    int*   cursor    = (int*)(ws + off); off = alignUp(off + (size_t)N * 4, 256);
    int*   csr_src   = (int*)(ws + off); off = alignUp(off + (size_t)E * 4, 256);
    int*   bsum      = (int*)(ws + off); off = alignUp(off + (size_t)512 * 4, 256);
    int*   gstart    = (int*)(ws + off); off = alignUp(off + (size_t)(G + 1) * 4, 256);
    float* agg       = (float*)(ws + off); off = alignUp(off + (size_t)N * 128 * 4, 256);
    float* h1        = (float*)(ws + off); off = alignUp(off + (size_t)N * 128 * 4, 256);
    float* pooled    = (float*)(ws + off); off = alignUp(off + (size_t)G * 128 * 4, 256);
    float* cnt       = (float*)(ws + off); off = alignUp(off + (size_t)G * 4, 256);
    (void)ws_size;

    // zero deg/cursor region only (pooled/cnt are fully written by k_pool_seg)
    hipMemsetAsync(deg, 0, (char*)csr_src - (char*)deg, stream);

    // CSR build
    k_count_deg<<<(E + 255) / 256, 256, 0, stream>>>(dst, deg, E);
    k_block_sum<<<nScanBlocks, 256, 0, stream>>>(deg, bsum, N);
    k_scan_bsum<<<1, 512, 0, stream>>>(bsum, nScanBlocks);
    k_scan_final<<<nScanBlocks, 256, 0, stream>>>(deg, bsum, row_start, N);
    k_scatter<<<(E + 255) / 256, 256, 0, stream>>>(src, dst, row_start, cursor, csr_src, E);

    // graph segment bounds from sorted batch
    k_graph_bounds<<<2, 256, 0, stream>>>(batch, gstart, N, G);

    // layer 1: agg(K=64) -> h1 = relu(agg@Wl1.T + bl1 + x@Wr1.T)
    k_gather_mean<64><<<(N + 3) / 4, 256, 0, stream>>>(x, row_start, deg, csr_src, agg, N);
    k_linear<64><<<(N + 63) / 64, 256, 0, stream>>>(agg, x, Wl1, bl1, Wr1, h1, N);

    // layer 2: agg2(K=128 from h1) -> h2 = relu(agg2@Wl2.T + bl2 + h1@Wr2.T)
    // h2 written in-place over agg (each block stores only its own rows, after reads)
    k_gather_mean<128><<<(N + 3) / 4, 256, 0, stream>>>(h1, row_start, deg, csr_src, agg, N);
    k_linear<128><<<(N + 63) / 64, 256, 0, stream>>>(agg, h1, Wl2, bl2, Wr2, agg, N);

    // pool (segmented, no atomics) + head
    k_pool_seg<<<G, 256, 0, stream>>>(agg, gstart, pooled, cnt);
    k_head<<<G, 64, 0, stream>>>(pooled, cnt, Wout, bout, out);
}

// Round 4
// 459.347 us; speedup vs baseline: 2.3822x; 1.2950x over previous
//
#include <hip/hip_runtime.h>
#include <hip/hip_bf16.h>
#include <math.h>

typedef short short8_t __attribute__((ext_vector_type(8)));
typedef float floatx4  __attribute__((ext_vector_type(4)));
typedef unsigned int uint;

// ---------------- bf16 helpers (RNE) ----------------------------------------

__device__ inline unsigned short f2b(float f) {
    uint u = __float_as_uint(f);
    u += 0x7fff + ((u >> 16) & 1);
    return (unsigned short)(u >> 16);
}
__device__ inline uint pack2(float a, float b) {
    return (uint)f2b(a) | ((uint)f2b(b) << 16);
}

// ---------------- CSR build ---------------------------------------------------

__global__ void k_count_deg(const int* __restrict__ dst, int* __restrict__ deg, int E) {
    int e = blockIdx.x * blockDim.x + threadIdx.x;
    if (e < E) atomicAdd(&deg[dst[e]], 1);
}

__global__ void k_block_sum(const int* __restrict__ deg, int* __restrict__ bsum, int n) {
    __shared__ int red[256];
    int i = blockIdx.x * 256 + threadIdx.x;
    red[threadIdx.x] = (i < n) ? deg[i] : 0;
    __syncthreads();
#pragma unroll
    for (int off = 128; off > 0; off >>= 1) {
        if (threadIdx.x < off) red[threadIdx.x] += red[threadIdx.x + off];
        __syncthreads();
    }
    if (threadIdx.x == 0) bsum[blockIdx.x] = red[0];
}

__global__ void k_scan_bsum(int* __restrict__ bsum, int nb) {
    __shared__ int s[512];
    int t = threadIdx.x;
    int v = (t < nb) ? bsum[t] : 0;
    s[t] = v;
    __syncthreads();
#pragma unroll
    for (int off = 1; off < 512; off <<= 1) {
        int u = (t >= off) ? s[t - off] : 0;
        __syncthreads();
        s[t] += u;
        __syncthreads();
    }
    if (t < nb) bsum[t] = s[t] - v;
}

__global__ void k_scan_final(const int* __restrict__ deg, const int* __restrict__ bsum,
                             int* __restrict__ row_start, int n) {
    __shared__ int s[256];
    int i = blockIdx.x * 256 + threadIdx.x;
    int v = (i < n) ? deg[i] : 0;
    s[threadIdx.x] = v;
    __syncthreads();
#pragma unroll
    for (int off = 1; off < 256; off <<= 1) {
        int u = (threadIdx.x >= off) ? s[threadIdx.x - off] : 0;
        __syncthreads();
        s[threadIdx.x] += u;
        __syncthreads();
    }
    int excl = s[threadIdx.x] - v + bsum[blockIdx.x];
    if (i < n) row_start[i] = excl;
    if (i == n - 1) row_start[n] = excl + v;
}

__global__ void k_scatter(const int* __restrict__ src, const int* __restrict__ dst,
                          const int* __restrict__ row_start, int* __restrict__ cursor,
                          int* __restrict__ csr_src, int E) {
    int e = blockIdx.x * blockDim.x + threadIdx.x;
    if (e >= E) return;
    int d = dst[e];
    int pos = atomicAdd(&cursor[d], 1);
    csr_src[row_start[d] + pos] = src[e];
}

// ---------------- fp32 -> bf16 conversions -----------------------------------

__global__ void k_cvt_x(const float* __restrict__ src, unsigned short* __restrict__ dst, int n) {
    int i = (blockIdx.x * blockDim.x + threadIdx.x) * 4;
    if (i >= n) return;
    float4 v = *(const float4*)(src + i);
    uint2 o;
    o.x = pack2(v.x, v.y);
    o.y = pack2(v.z, v.w);
    *(uint2*)(dst + i) = o;
}

// wbuf layout: Wl1b[8192] | Wr1b[8192] | Wl2b[16384] | Wr2b[16384]
__global__ void k_cvt_w(const float* __restrict__ Wl1, const float* __restrict__ Wr1,
                        const float* __restrict__ Wl2, const float* __restrict__ Wr2,
                        unsigned short* __restrict__ wbuf) {
    int i = blockIdx.x * blockDim.x + threadIdx.x;
    if (i >= 49152) return;
    float v;
    if (i < 8192)       v = Wl1[i];
    else if (i < 16384) v = Wr1[i - 8192];
    else if (i < 32768) v = Wl2[i - 16384];
    else                v = Wr2[i - 32768];
    wbuf[i] = f2b(v);
}

// ---------------- mean aggregation (bf16 in, bf16 out, fp32 accumulate) ------

// K=64: one node per wave; lane = (channel-pair c2 in 0..31) x (edge parity)
__global__ void k_gather1(const unsigned short* __restrict__ xb,
                          const int* __restrict__ row_start,
                          const int* __restrict__ deg,
                          const int* __restrict__ csr_src,
                          unsigned short* __restrict__ agg, int n_nodes) {
    int tid = threadIdx.x;
    int node = blockIdx.x * 4 + (tid >> 6);
    if (node >= n_nodes) return;
    int lane = tid & 63;
    int c2 = lane & 31;
    int par = lane >> 5;
    int s = row_start[node];
    int d = deg[node];
    float a0 = 0.f, a1 = 0.f;
    for (int i = s + par; i < s + d; i += 2) {
        int u = csr_src[i];
        uint v = *(const uint*)(xb + (size_t)u * 64 + c2 * 2);
        a0 += __uint_as_float(v << 16);
        a1 += __uint_as_float(v & 0xffff0000u);
    }
    a0 += __shfl_xor(a0, 32);
    a1 += __shfl_xor(a1, 32);
    if (par == 0) {
        float scale = (d > 0) ? (1.f / (float)d) : 1.f;
        ((uint*)agg)[(size_t)node * 32 + c2] = pack2(a0 * scale, a1 * scale);
    }
}

// K=128: one node per wave; lane = channel pair (0..63)
__global__ void k_gather2(const unsigned short* __restrict__ h1,
                          const int* __restrict__ row_start,
                          const int* __restrict__ deg,
                          const int* __restrict__ csr_src,
                          unsigned short* __restrict__ agg, int n_nodes) {
    int tid = threadIdx.x;
    int node = blockIdx.x * 4 + (tid >> 6);
    if (node >= n_nodes) return;
    int lane = tid & 63;
    int s = row_start[node];
    int d = deg[node];
    float a0 = 0.f, a1 = 0.f;
    for (int i = s; i < s + d; ++i) {
        int u = csr_src[i];
        uint v = *(const uint*)(h1 + (size_t)u * 128 + lane * 2);
        a0 += __uint_as_float(v << 16);
        a1 += __uint_as_float(v & 0xffff0000u);
    }
    float scale = (d > 0) ? (1.f / (float)d) : 1.f;
    ((uint*)agg)[(size_t)node * 64 + lane] = pack2(a0 * scale, a1 * scale);
}

// ---------------- MFMA SAGE linear: out = relu(agg@Wl.T + bl + xin@Wr.T) ----
// bf16 inputs, fp32 MFMA accumulate. Tile 128 nodes x 128 j, 4 waves.
// Wave w covers j in [w*32, w*32+32): two 16-wide n-subtiles.
// A staged per 32-k chunk in LDS [128][32] bf16 (lane-linear, conflict-free).
// B fragments read directly from global bf16 weights (L1/L2 broadcast).

template <typename OutT>
__device__ inline void store_out(OutT* p, float v);
template <> __device__ inline void store_out<float>(float* p, float v) { *p = v; }
template <> __device__ inline void store_out<unsigned short>(unsigned short* p, float v) { *p = f2b(v); }

template <int K, typename OutT>
__global__ __launch_bounds__(256) void k_linear_mfma(
    const unsigned short* __restrict__ aggA, const unsigned short* __restrict__ xinA,
    const unsigned short* __restrict__ Wlb,  const float* __restrict__ bl,
    const unsigned short* __restrict__ Wrb,  OutT* __restrict__ out, int n_nodes) {
    constexpr int NCH = (2 * K) / 32;
    __shared__ __align__(16) short As[128 * 32];   // 8 KB

    int tid  = threadIdx.x;
    int lane = tid & 63;
    int wave = tid >> 6;
    int quad = lane >> 4;
    int lr   = lane & 15;
    int node0 = blockIdx.x * 128;

    floatx4 acc[8][2];
#pragma unroll
    for (int mi = 0; mi < 8; ++mi)
#pragma unroll
        for (int ni = 0; ni < 2; ++ni)
            acc[mi][ni] = (floatx4){0.f, 0.f, 0.f, 0.f};

    // staging coords (fixed per thread)
    int srow = tid >> 2;        // 0..63
    int sslot = tid & 3;        // 16B slot within 64B row-chunk

#pragma unroll
    for (int c = 0; c < NCH; ++c) {
        const unsigned short* srcA;
        const unsigned short* srcW;
        int kb;
        if (c < K / 32) { srcA = aggA; srcW = Wlb; kb = c * 32; }
        else            { srcA = xinA; srcW = Wrb; kb = c * 32 - K; }

        __syncthreads();   // previous chunk's LDS reads done
        {
            int n1 = node0 + srow;       if (n1 >= n_nodes) n1 = n_nodes - 1;
            int n2 = node0 + srow + 64;  if (n2 >= n_nodes) n2 = n_nodes - 1;
            uint4 v1 = *(const uint4*)(srcA + (size_t)n1 * K + kb + sslot * 8);
            uint4 v2 = *(const uint4*)(srcA + (size_t)n2 * K + kb + sslot * 8);
            *(uint4*)(&As[srow * 32 + sslot * 8]) = v1;
            *(uint4*)(&As[(srow + 64) * 32 + sslot * 8]) = v2;
        }
        __syncthreads();

        short8_t bfrag[2];
#pragma unroll
        for (int ni = 0; ni < 2; ++ni) {
            int j = wave * 32 + ni * 16 + lr;
            bfrag[ni] = *(const short8_t*)(srcW + (size_t)j * K + kb + quad * 8);
        }
#pragma unroll
        for (int mi = 0; mi < 8; ++mi) {
            short8_t af = *(const short8_t*)(&As[(mi * 16 + lr) * 32 + quad * 8]);
            acc[mi][0] = __builtin_amdgcn_mfma_f32_16x16x32_bf16(af, bfrag[0], acc[mi][0], 0, 0, 0);
            acc[mi][1] = __builtin_amdgcn_mfma_f32_16x16x32_bf16(af, bfrag[1], acc[mi][1], 0, 0, 0);
        }
    }

    // epilogue: bias + relu + store. C/D: col(n)=lane&15, row(m)=quad*4+reg.
    float b0 = bl[wave * 32 + lr];
    float b1 = bl[wave * 32 + 16 + lr];
    int j0 = wave * 32 + lr;
#pragma unroll
    for (int mi = 0; mi < 8; ++mi) {
#pragma unroll
        for (int r = 0; r < 4; ++r) {
            int node = node0 + mi * 16 + quad * 4 + r;
            if (node < n_nodes) {
                float v0 = fmaxf(acc[mi][0][r] + b0, 0.f);
                float v1 = fmaxf(acc[mi][1][r] + b1, 0.f);
                store_out(out + (size_t)node * 128 + j0, v0);
                store_out(out + (size_t)node * 128 + j0 + 16, v1);
            }
        }
    }
}

// ---------------- pooling: batch is SORTED -> segmented reduction ------------

__global__ void k_graph_bounds(const int* __restrict__ batch, int* __restrict__ gstart,
                               int N, int G) {
    int g = blockIdx.x * blockDim.x + threadIdx.x;
    if (g > G) return;
    if (g == G) { gstart[G] = N; return; }
    int lo = 0, hi = N;
    while (lo < hi) {
        int mid = (lo + hi) >> 1;
        if (batch[mid] < g) lo = mid + 1; else hi = mid;
    }
    gstart[g] = lo;
}

__global__ __launch_bounds__(256) void k_pool_seg(const float* __restrict__ h2,
                                                  const int* __restrict__ gstart,
                                                  float* __restrict__ pooled,
                                                  float* __restrict__ cnt) {
    int g = blockIdx.x;
    int s = gstart[g], e = gstart[g + 1];
    int lane = threadIdx.x & 63;
    int wave = threadIdx.x >> 6;
    float ax = 0.f, ay = 0.f;
    for (int n = s + wave; n < e; n += 4) {
        float2 v = ((const float2*)(h2 + (size_t)n * 128))[lane];
        ax += v.x; ay += v.y;
    }
    __shared__ float2 red[4][64];
    red[wave][lane] = make_float2(ax, ay);
    __syncthreads();
    if (wave == 0) {
        float2 a = red[0][lane], b = red[1][lane], c = red[2][lane], d = red[3][lane];
        float2 o;
        o.x = a.x + b.x + c.x + d.x;
        o.y = a.y + b.y + c.y + d.y;
        ((float2*)(pooled + g * 128))[lane] = o;
        if (lane == 0) cnt[g] = (float)(e - s);
    }
}

// ---------------- head: mean, linear [2x128], log_softmax -------------------

__global__ void k_head(const float* __restrict__ pooled, const float* __restrict__ cnt,
                       const float* __restrict__ Wout, const float* __restrict__ bout,
                       float* __restrict__ out) {
    int g = blockIdx.x;
    int lane = threadIdx.x;
    float c = cnt[g];
    float inv = (c > 0.f) ? (1.f / c) : 1.f;
    float2 p  = ((const float2*)(pooled + g * 128))[lane];
    p.x *= inv; p.y *= inv;
    float2 w0 = ((const float2*)(Wout))[lane];
    float2 w1 = ((const float2*)(Wout + 128))[lane];
    float d0 = p.x * w0.x + p.y * w0.y;
    float d1 = p.x * w1.x + p.y * w1.y;
#pragma unroll
    for (int m = 32; m > 0; m >>= 1) {
        d0 += __shfl_xor(d0, m);
        d1 += __shfl_xor(d1, m);
    }
    if (lane == 0) {
        float l0 = d0 + bout[0];
        float l1 = d1 + bout[1];
        float mx = fmaxf(l0, l1);
        float lse = mx + logf(expf(l0 - mx) + expf(l1 - mx));
        out[g * 2 + 0] = l0 - lse;
        out[g * 2 + 1] = l1 - lse;
    }
}

// ---------------- launch -----------------------------------------------------

static inline size_t alignUp(size_t x, size_t a) { return (x + a - 1) & ~(a - 1); }

extern "C" void kernel_launch(void* const* d_in, const int* in_sizes, int n_in,
                              void* d_out, int out_size, void* d_ws, size_t ws_size,
                              hipStream_t stream) {
    const float* x    = (const float*)d_in[0];
    const int*   ei   = (const int*)d_in[1];
    const int*   batch= (const int*)d_in[2];
    const float* Wl1  = (const float*)d_in[3];
    const float* bl1  = (const float*)d_in[4];
    const float* Wr1  = (const float*)d_in[5];
    const float* Wl2  = (const float*)d_in[6];
    const float* bl2  = (const float*)d_in[7];
    const float* Wr2  = (const float*)d_in[8];
    const float* Wout = (const float*)d_in[9];
    const float* bout = (const float*)d_in[10];
    float* out = (float*)d_out;

    const int N = in_sizes[0] / 64;   // 100000
    const int E = in_sizes[1] / 2;    // 1000000
    const int G = out_size / 2;       // 256

    const int* src = ei;
    const int* dst = ei + E;

    const int nScanBlocks = (N + 255) / 256;

    // workspace layout
    char* ws = (char*)d_ws;
    size_t off = 0;
    int*   deg       = (int*)(ws + off); off = alignUp(off + (size_t)N * 4, 256);
    int*   row_start = (int*)(ws + off); off = alignUp(off + (size_t)(N + 1) * 4, 256);
    int*   cursor    = (int*)(ws + off); off = alignUp(off + (size_t)N * 4, 256);
    int*   csr_src   = (int*)(ws + off); off = alignUp(off + (size_t)E * 4, 256);
    int*   bsum      = (int*)(ws + off); off = alignUp(off + (size_t)512 * 4, 256);
    int*   gstart    = (int*)(ws + off); off = alignUp(off + (size_t)(G + 1) * 4, 256);
    unsigned short* xb   = (unsigned short*)(ws + off); off = alignUp(off + (size_t)N * 64 * 2, 256);
    unsigned short* wbuf = (unsigned short*)(ws + off); off = alignUp(off + (size_t)49152 * 2, 256);
    unsigned short* agg1 = (unsigned short*)(ws + off); off = alignUp(off + (size_t)N * 64 * 2, 256);
    unsigned short* h1   = (unsigned short*)(ws + off); off = alignUp(off + (size_t)N * 128 * 2, 256);
    unsigned short* agg2 = (unsigned short*)(ws + off); off = alignUp(off + (size_t)N * 128 * 2, 256);
    float* h2        = (float*)(ws + off); off = alignUp(off + (size_t)N * 128 * 4, 256);
    float* pooled    = (float*)(ws + off); off = alignUp(off + (size_t)G * 128 * 4, 256);
    float* cnt       = (float*)(ws + off); off = alignUp(off + (size_t)G * 4, 256);
    (void)ws_size;

    unsigned short* Wl1b = wbuf;
    unsigned short* Wr1b = wbuf + 8192;
    unsigned short* Wl2b = wbuf + 16384;
    unsigned short* Wr2b = wbuf + 32768;

    // zero deg/row_start/cursor region
    hipMemsetAsync(deg, 0, (char*)csr_src - (char*)deg, stream);

    // conversions
    k_cvt_x<<<(N * 64 / 4 + 255) / 256, 256, 0, stream>>>(x, xb, N * 64);
    k_cvt_w<<<192, 256, 0, stream>>>(Wl1, Wr1, Wl2, Wr2, wbuf);

    // CSR build
    k_count_deg<<<(E + 255) / 256, 256, 0, stream>>>(dst, deg, E);
    k_block_sum<<<nScanBlocks, 256, 0, stream>>>(deg, bsum, N);
    k_scan_bsum<<<1, 512, 0, stream>>>(bsum, nScanBlocks);
    k_scan_final<<<nScanBlocks, 256, 0, stream>>>(deg, bsum, row_start, N);
    k_scatter<<<(E + 255) / 256, 256, 0, stream>>>(src, dst, row_start, cursor, csr_src, E);

    // graph segment bounds from sorted batch
    k_graph_bounds<<<2, 256, 0, stream>>>(batch, gstart, N, G);

    // layer 1
    k_gather1<<<(N + 3) / 4, 256, 0, stream>>>(xb, row_start, deg, csr_src, agg1, N);
    k_linear_mfma<64, unsigned short><<<(N + 127) / 128, 256, 0, stream>>>(
        agg1, xb, Wl1b, bl1, Wr1b, h1, N);

    // layer 2
    k_gather2<<<(N + 3) / 4, 256, 0, stream>>>(h1, row_start, deg, csr_src, agg2, N);
    k_linear_mfma<128, float><<<(N + 127) / 128, 256, 0, stream>>>(
        agg2, h1, Wl2b, bl2, Wr2b, h2, N);

    // pool + head
    k_pool_seg<<<G, 256, 0, stream>>>(h2, gstart, pooled, cnt);
    k_head<<<G, 64, 0, stream>>>(pooled, cnt, Wout, bout, out);
}

// Round 5
// 337.793 us; speedup vs baseline: 3.2394x; 1.3598x over previous
//
#include <hip/hip_runtime.h>
#include <hip/hip_bf16.h>
#include <math.h>

typedef short short8_t __attribute__((ext_vector_type(8)));
typedef float floatx4  __attribute__((ext_vector_type(4)));
typedef unsigned int uint;

// ---------------- bf16 helpers (RNE) ----------------------------------------

__device__ inline unsigned short f2b(float f) {
    uint u = __float_as_uint(f);
    u += 0x7fff + ((u >> 16) & 1);
    return (unsigned short)(u >> 16);
}
__device__ inline uint pack2(float a, float b) {
    return (uint)f2b(a) | ((uint)f2b(b) << 16);
}

// ---------------- CSR build ---------------------------------------------------

// one pass: count AND record each edge's slot within its dst bucket
__global__ void k_count_pos(const int* __restrict__ dst, int* __restrict__ deg,
                            int* __restrict__ epos, int E) {
    int e = blockIdx.x * blockDim.x + threadIdx.x;
    if (e < E) epos[e] = atomicAdd(&deg[dst[e]], 1);
}

__global__ void k_block_sum(const int* __restrict__ deg, int* __restrict__ bsum, int n) {
    __shared__ int red[256];
    int i = blockIdx.x * 256 + threadIdx.x;
    red[threadIdx.x] = (i < n) ? deg[i] : 0;
    __syncthreads();
#pragma unroll
    for (int off = 128; off > 0; off >>= 1) {
        if (threadIdx.x < off) red[threadIdx.x] += red[threadIdx.x + off];
        __syncthreads();
    }
    if (threadIdx.x == 0) bsum[blockIdx.x] = red[0];
}

__global__ void k_scan_bsum(int* __restrict__ bsum, int nb) {
    __shared__ int s[512];
    int t = threadIdx.x;
    int v = (t < nb) ? bsum[t] : 0;
    s[t] = v;
    __syncthreads();
#pragma unroll
    for (int off = 1; off < 512; off <<= 1) {
        int u = (t >= off) ? s[t - off] : 0;
        __syncthreads();
        s[t] += u;
        __syncthreads();
    }
    if (t < nb) bsum[t] = s[t] - v;
}

__global__ void k_scan_final(const int* __restrict__ deg, const int* __restrict__ bsum,
                             int* __restrict__ row_start, int n) {
    __shared__ int s[256];
    int i = blockIdx.x * 256 + threadIdx.x;
    int v = (i < n) ? deg[i] : 0;
    s[threadIdx.x] = v;
    __syncthreads();
#pragma unroll
    for (int off = 1; off < 256; off <<= 1) {
        int u = (threadIdx.x >= off) ? s[threadIdx.x - off] : 0;
        __syncthreads();
        s[threadIdx.x] += u;
        __syncthreads();
    }
    int excl = s[threadIdx.x] - v + bsum[blockIdx.x];
    if (i < n) row_start[i] = excl;
    if (i == n - 1) row_start[n] = excl + v;
}

// atomic-free placement using precomputed slots
__global__ void k_place(const int* __restrict__ src, const int* __restrict__ dst,
                        const int* __restrict__ row_start, const int* __restrict__ epos,
                        int* __restrict__ csr_src, int E) {
    int e = blockIdx.x * blockDim.x + threadIdx.x;
    if (e >= E) return;
    csr_src[row_start[dst[e]] + epos[e]] = src[e];
}

// ---------------- fp32 -> bf16 conversions -----------------------------------

__global__ void k_cvt_x(const float* __restrict__ src, unsigned short* __restrict__ dst, int n) {
    int i = (blockIdx.x * blockDim.x + threadIdx.x) * 4;
    if (i >= n) return;
    float4 v = *(const float4*)(src + i);
    uint2 o;
    o.x = pack2(v.x, v.y);
    o.y = pack2(v.z, v.w);
    *(uint2*)(dst + i) = o;
}

// wbuf layout: Wl1b[8192] | Wr1b[8192] | Wl2b[16384] | Wr2b[16384]
__global__ void k_cvt_w(const float* __restrict__ Wl1, const float* __restrict__ Wr1,
                        const float* __restrict__ Wl2, const float* __restrict__ Wr2,
                        unsigned short* __restrict__ wbuf) {
    int i = blockIdx.x * blockDim.x + threadIdx.x;
    if (i >= 49152) return;
    float v;
    if (i < 8192)       v = Wl1[i];
    else if (i < 16384) v = Wr1[i - 8192];
    else if (i < 32768) v = Wl2[i - 16384];
    else                v = Wr2[i - 32768];
    wbuf[i] = f2b(v);
}

// ---------------- mean aggregation (bf16 in/out, fp32 accumulate) ------------
// Wide-load edge-slot design: each wave handles one node; lanes split into
// edge-slots x 16B-load groups so one load instruction fetches multiple
// neighbor rows (memory-level parallelism for the latency-bound gather).

// K=64: row = 128 B. 8 edge-slots x 8 lanes x uint4. Reduce over slots.
__global__ void k_gather1(const unsigned short* __restrict__ xb,
                          const int* __restrict__ row_start,
                          const int* __restrict__ csr_src,
                          unsigned short* __restrict__ agg, int n_nodes) {
    int tid = threadIdx.x;
    int node = blockIdx.x * 4 + (tid >> 6);
    if (node >= n_nodes) return;
    int lane = tid & 63;
    int grp = lane >> 3;       // edge slot 0..7
    int lp  = lane & 7;        // 8 lanes x 16B = 128 B row
    int s = row_start[node];
    int e = row_start[node + 1];
    float a[8];
#pragma unroll
    for (int q = 0; q < 8; ++q) a[q] = 0.f;
    for (int i = s + grp; i < e; i += 8) {
        int u = csr_src[i];
        uint4 v = *(const uint4*)(xb + (size_t)u * 64 + lp * 8);
        a[0] += __uint_as_float(v.x << 16);
        a[1] += __uint_as_float(v.x & 0xffff0000u);
        a[2] += __uint_as_float(v.y << 16);
        a[3] += __uint_as_float(v.y & 0xffff0000u);
        a[4] += __uint_as_float(v.z << 16);
        a[5] += __uint_as_float(v.z & 0xffff0000u);
        a[6] += __uint_as_float(v.w << 16);
        a[7] += __uint_as_float(v.w & 0xffff0000u);
    }
#pragma unroll
    for (int q = 0; q < 8; ++q) {
        a[q] += __shfl_xor(a[q], 8);
        a[q] += __shfl_xor(a[q], 16);
        a[q] += __shfl_xor(a[q], 32);
    }
    if (grp == 0) {
        int d = e - s;
        float scale = (d > 0) ? (1.f / (float)d) : 1.f;
        uint4 o;
        o.x = pack2(a[0] * scale, a[1] * scale);
        o.y = pack2(a[2] * scale, a[3] * scale);
        o.z = pack2(a[4] * scale, a[5] * scale);
        o.w = pack2(a[6] * scale, a[7] * scale);
        *(uint4*)(agg + (size_t)node * 64 + lp * 8) = o;
    }
}

// K=128: row = 256 B. 4 edge-slots x 16 lanes x uint4. Reduce over slots.
__global__ void k_gather2(const unsigned short* __restrict__ h1,
                          const int* __restrict__ row_start,
                          const int* __restrict__ csr_src,
                          unsigned short* __restrict__ agg, int n_nodes) {
    int tid = threadIdx.x;
    int node = blockIdx.x * 4 + (tid >> 6);
    if (node >= n_nodes) return;
    int lane = tid & 63;
    int grp = lane >> 4;       // edge slot 0..3
    int lp  = lane & 15;       // 16 lanes x 16B = 256 B row
    int s = row_start[node];
    int e = row_start[node + 1];
    float a[8];
#pragma unroll
    for (int q = 0; q < 8; ++q) a[q] = 0.f;
    for (int i = s + grp; i < e; i += 4) {
        int u = csr_src[i];
        uint4 v = *(const uint4*)(h1 + (size_t)u * 128 + lp * 8);
        a[0] += __uint_as_float(v.x << 16);
        a[1] += __uint_as_float(v.x & 0xffff0000u);
        a[2] += __uint_as_float(v.y << 16);
        a[3] += __uint_as_float(v.y & 0xffff0000u);
        a[4] += __uint_as_float(v.z << 16);
        a[5] += __uint_as_float(v.z & 0xffff0000u);
        a[6] += __uint_as_float(v.w << 16);
        a[7] += __uint_as_float(v.w & 0xffff0000u);
    }
#pragma unroll
    for (int q = 0; q < 8; ++q) {
        a[q] += __shfl_xor(a[q], 16);
        a[q] += __shfl_xor(a[q], 32);
    }
    if (grp == 0) {
        int d = e - s;
        float scale = (d > 0) ? (1.f / (float)d) : 1.f;
        uint4 o;
        o.x = pack2(a[0] * scale, a[1] * scale);
        o.y = pack2(a[2] * scale, a[3] * scale);
        o.z = pack2(a[4] * scale, a[5] * scale);
        o.w = pack2(a[6] * scale, a[7] * scale);
        *(uint4*)(agg + (size_t)node * 128 + lp * 8) = o;
    }
}

// ---------------- MFMA SAGE linear: out = relu(agg@Wl.T + bl + xin@Wr.T) ----

template <typename OutT>
__device__ inline void store_out(OutT* p, float v);
template <> __device__ inline void store_out<float>(float* p, float v) { *p = v; }
template <> __device__ inline void store_out<unsigned short>(unsigned short* p, float v) { *p = f2b(v); }

template <int K, typename OutT>
__global__ __launch_bounds__(256) void k_linear_mfma(
    const unsigned short* __restrict__ aggA, const unsigned short* __restrict__ xinA,
    const unsigned short* __restrict__ Wlb,  const float* __restrict__ bl,
    const unsigned short* __restrict__ Wrb,  OutT* __restrict__ out, int n_nodes) {
    constexpr int NCH = (2 * K) / 32;
    __shared__ __align__(16) short As[128 * 32];   // 8 KB

    int tid  = threadIdx.x;
    int lane = tid & 63;
    int wave = tid >> 6;
    int quad = lane >> 4;
    int lr   = lane & 15;
    int node0 = blockIdx.x * 128;

    floatx4 acc[8][2];
#pragma unroll
    for (int mi = 0; mi < 8; ++mi)
#pragma unroll
        for (int ni = 0; ni < 2; ++ni)
            acc[mi][ni] = (floatx4){0.f, 0.f, 0.f, 0.f};

    int srow = tid >> 2;
    int sslot = tid & 3;

#pragma unroll
    for (int c = 0; c < NCH; ++c) {
        const unsigned short* srcA;
        const unsigned short* srcW;
        int kb;
        if (c < K / 32) { srcA = aggA; srcW = Wlb; kb = c * 32; }
        else            { srcA = xinA; srcW = Wrb; kb = c * 32 - K; }

        __syncthreads();
        {
            int n1 = node0 + srow;       if (n1 >= n_nodes) n1 = n_nodes - 1;
            int n2 = node0 + srow + 64;  if (n2 >= n_nodes) n2 = n_nodes - 1;
            uint4 v1 = *(const uint4*)(srcA + (size_t)n1 * K + kb + sslot * 8);
            uint4 v2 = *(const uint4*)(srcA + (size_t)n2 * K + kb + sslot * 8);
            *(uint4*)(&As[srow * 32 + sslot * 8]) = v1;
            *(uint4*)(&As[(srow + 64) * 32 + sslot * 8]) = v2;
        }
        __syncthreads();

        short8_t bfrag[2];
#pragma unroll
        for (int ni = 0; ni < 2; ++ni) {
            int j = wave * 32 + ni * 16 + lr;
            bfrag[ni] = *(const short8_t*)(srcW + (size_t)j * K + kb + quad * 8);
        }
#pragma unroll
        for (int mi = 0; mi < 8; ++mi) {
            short8_t af = *(const short8_t*)(&As[(mi * 16 + lr) * 32 + quad * 8]);
            acc[mi][0] = __builtin_amdgcn_mfma_f32_16x16x32_bf16(af, bfrag[0], acc[mi][0], 0, 0, 0);
            acc[mi][1] = __builtin_amdgcn_mfma_f32_16x16x32_bf16(af, bfrag[1], acc[mi][1], 0, 0, 0);
        }
    }

    float b0 = bl[wave * 32 + lr];
    float b1 = bl[wave * 32 + 16 + lr];
    int j0 = wave * 32 + lr;
#pragma unroll
    for (int mi = 0; mi < 8; ++mi) {
#pragma unroll
        for (int r = 0; r < 4; ++r) {
            int node = node0 + mi * 16 + quad * 4 + r;
            if (node < n_nodes) {
                float v0 = fmaxf(acc[mi][0][r] + b0, 0.f);
                float v1 = fmaxf(acc[mi][1][r] + b1, 0.f);
                store_out(out + (size_t)node * 128 + j0, v0);
                store_out(out + (size_t)node * 128 + j0 + 16, v1);
            }
        }
    }
}

// ---------------- pooling: batch is SORTED -> segmented reduction ------------

__global__ void k_graph_bounds(const int* __restrict__ batch, int* __restrict__ gstart,
                               int N, int G) {
    int g = blockIdx.x * blockDim.x + threadIdx.x;
    if (g > G) return;
    if (g == G) { gstart[G] = N; return; }
    int lo = 0, hi = N;
    while (lo < hi) {
        int mid = (lo + hi) >> 1;
        if (batch[mid] < g) lo = mid + 1; else hi = mid;
    }
    gstart[g] = lo;
}

__global__ __launch_bounds__(256) void k_pool_seg(const float* __restrict__ h2,
                                                  const int* __restrict__ gstart,
                                                  float* __restrict__ pooled,
                                                  float* __restrict__ cnt) {
    int g = blockIdx.x;
    int s = gstart[g], e = gstart[g + 1];
    int lane = threadIdx.x & 63;
    int wave = threadIdx.x >> 6;
    float ax = 0.f, ay = 0.f;
    for (int n = s + wave; n < e; n += 4) {
        float2 v = ((const float2*)(h2 + (size_t)n * 128))[lane];
        ax += v.x; ay += v.y;
    }
    __shared__ float2 red[4][64];
    red[wave][lane] = make_float2(ax, ay);
    __syncthreads();
    if (wave == 0) {
        float2 a = red[0][lane], b = red[1][lane], c = red[2][lane], d = red[3][lane];
        float2 o;
        o.x = a.x + b.x + c.x + d.x;
        o.y = a.y + b.y + c.y + d.y;
        ((float2*)(pooled + g * 128))[lane] = o;
        if (lane == 0) cnt[g] = (float)(e - s);
    }
}

// ---------------- head: mean, linear [2x128], log_softmax -------------------

__global__ void k_head(const float* __restrict__ pooled, const float* __restrict__ cnt,
                       const float* __restrict__ Wout, const float* __restrict__ bout,
                       float* __restrict__ out) {
    int g = blockIdx.x;
    int lane = threadIdx.x;
    float c = cnt[g];
    float inv = (c > 0.f) ? (1.f / c) : 1.f;
    float2 p  = ((const float2*)(pooled + g * 128))[lane];
    p.x *= inv; p.y *= inv;
    float2 w0 = ((const float2*)(Wout))[lane];
    float2 w1 = ((const float2*)(Wout + 128))[lane];
    float d0 = p.x * w0.x + p.y * w0.y;
    float d1 = p.x * w1.x + p.y * w1.y;
#pragma unroll
    for (int m = 32; m > 0; m >>= 1) {
        d0 += __shfl_xor(d0, m);
        d1 += __shfl_xor(d1, m);
    }
    if (lane == 0) {
        float l0 = d0 + bout[0];
        float l1 = d1 + bout[1];
        float mx = fmaxf(l0, l1);
        float lse = mx + logf(expf(l0 - mx) + expf(l1 - mx));
        out[g * 2 + 0] = l0 - lse;
        out[g * 2 + 1] = l1 - lse;
    }
}

// ---------------- launch -----------------------------------------------------

static inline size_t alignUp(size_t x, size_t a) { return (x + a - 1) & ~(a - 1); }

extern "C" void kernel_launch(void* const* d_in, const int* in_sizes, int n_in,
                              void* d_out, int out_size, void* d_ws, size_t ws_size,
                              hipStream_t stream) {
    const float* x    = (const float*)d_in[0];
    const int*   ei   = (const int*)d_in[1];
    const int*   batch= (const int*)d_in[2];
    const float* Wl1  = (const float*)d_in[3];
    const float* bl1  = (const float*)d_in[4];
    const float* Wr1  = (const float*)d_in[5];
    const float* Wl2  = (const float*)d_in[6];
    const float* bl2  = (const float*)d_in[7];
    const float* Wr2  = (const float*)d_in[8];
    const float* Wout = (const float*)d_in[9];
    const float* bout = (const float*)d_in[10];
    float* out = (float*)d_out;

    const int N = in_sizes[0] / 64;   // 100000
    const int E = in_sizes[1] / 2;    // 1000000
    const int G = out_size / 2;       // 256

    const int* src = ei;
    const int* dst = ei + E;

    const int nScanBlocks = (N + 255) / 256;

    // workspace layout
    char* ws = (char*)d_ws;
    size_t off = 0;
    int*   deg       = (int*)(ws + off); off = alignUp(off + (size_t)N * 4, 256);
    int*   row_start = (int*)(ws + off); off = alignUp(off + (size_t)(N + 1) * 4, 256);
    int*   epos      = (int*)(ws + off); off = alignUp(off + (size_t)E * 4, 256);
    int*   csr_src   = (int*)(ws + off); off = alignUp(off + (size_t)E * 4, 256);
    int*   bsum      = (int*)(ws + off); off = alignUp(off + (size_t)512 * 4, 256);
    int*   gstart    = (int*)(ws + off); off = alignUp(off + (size_t)(G + 1) * 4, 256);
    unsigned short* xb   = (unsigned short*)(ws + off); off = alignUp(off + (size_t)N * 64 * 2, 256);
    unsigned short* wbuf = (unsigned short*)(ws + off); off = alignUp(off + (size_t)49152 * 2, 256);
    unsigned short* agg1 = (unsigned short*)(ws + off); off = alignUp(off + (size_t)N * 64 * 2, 256);
    unsigned short* h1   = (unsigned short*)(ws + off); off = alignUp(off + (size_t)N * 128 * 2, 256);
    unsigned short* agg2 = (unsigned short*)(ws + off); off = alignUp(off + (size_t)N * 128 * 2, 256);
    float* h2        = (float*)(ws + off); off = alignUp(off + (size_t)N * 128 * 4, 256);
    float* pooled    = (float*)(ws + off); off = alignUp(off + (size_t)G * 128 * 4, 256);
    float* cnt       = (float*)(ws + off); off = alignUp(off + (size_t)G * 4, 256);
    (void)ws_size;

    unsigned short* Wl1b = wbuf;
    unsigned short* Wr1b = wbuf + 8192;
    unsigned short* Wl2b = wbuf + 16384;
    unsigned short* Wr2b = wbuf + 32768;

    // zero deg only
    hipMemsetAsync(deg, 0, (size_t)N * 4, stream);

    // conversions
    k_cvt_x<<<(N * 64 / 4 + 255) / 256, 256, 0, stream>>>(x, xb, N * 64);
    k_cvt_w<<<192, 256, 0, stream>>>(Wl1, Wr1, Wl2, Wr2, wbuf);

    // CSR build (single atomic pass + scan + atomic-free placement)
    k_count_pos<<<(E + 255) / 256, 256, 0, stream>>>(dst, deg, epos, E);
    k_block_sum<<<nScanBlocks, 256, 0, stream>>>(deg, bsum, N);
    k_scan_bsum<<<1, 512, 0, stream>>>(bsum, nScanBlocks);
    k_scan_final<<<nScanBlocks, 256, 0, stream>>>(deg, bsum, row_start, N);
    k_place<<<(E + 255) / 256, 256, 0, stream>>>(src, dst, row_start, epos, csr_src, E);

    // graph segment bounds from sorted batch
    k_graph_bounds<<<2, 256, 0, stream>>>(batch, gstart, N, G);

    // layer 1
    k_gather1<<<(N + 3) / 4, 256, 0, stream>>>(xb, row_start, csr_src, agg1, N);
    k_linear_mfma<64, unsigned short><<<(N + 127) / 128, 256, 0, stream>>>(
        agg1, xb, Wl1b, bl1, Wr1b, h1, N);

    // layer 2
    k_gather2<<<(N + 3) / 4, 256, 0, stream>>>(h1, row_start, csr_src, agg2, N);
    k_linear_mfma<128, float><<<(N + 127) / 128, 256, 0, stream>>>(
        agg2, h1, Wl2b, bl2, Wr2b, h2, N);

    // pool + head
    k_pool_seg<<<G, 256, 0, stream>>>(h2, gstart, pooled, cnt);
    k_head<<<G, 64, 0, stream>>>(pooled, cnt, Wout, bout, out);
}

// Round 6
// 335.087 us; speedup vs baseline: 3.2656x; 1.0081x over previous
//
#include <hip/hip_runtime.h>
#include <hip/hip_bf16.h>
#include <math.h>

typedef short short8_t __attribute__((ext_vector_type(8)));
typedef float floatx4  __attribute__((ext_vector_type(4)));
typedef unsigned int uint;

// ---------------- bf16 helpers (RNE) ----------------------------------------

__device__ inline unsigned short f2b(float f) {
    uint u = __float_as_uint(f);
    u += 0x7fff + ((u >> 16) & 1);
    return (unsigned short)(u >> 16);
}
__device__ inline uint pack2(float a, float b) {
    return (uint)f2b(a) | ((uint)f2b(b) << 16);
}

// ---------------- CSR build ---------------------------------------------------

// one pass: count AND record each edge's slot within its dst bucket (4 edges/thread)
__global__ void k_count_pos(const int* __restrict__ dst, int* __restrict__ deg,
                            int* __restrict__ epos, int E) {
    int e = (blockIdx.x * blockDim.x + threadIdx.x) * 4;
    if (e + 3 < E) {
        int4 d4 = *(const int4*)(dst + e);
        int4 p;
        p.x = atomicAdd(&deg[d4.x], 1);
        p.y = atomicAdd(&deg[d4.y], 1);
        p.z = atomicAdd(&deg[d4.z], 1);
        p.w = atomicAdd(&deg[d4.w], 1);
        *(int4*)(epos + e) = p;
    } else {
        for (int k = e; k < E; ++k) epos[k] = atomicAdd(&deg[dst[k]], 1);
    }
}

__global__ void k_block_sum(const int* __restrict__ deg, int* __restrict__ bsum, int n) {
    __shared__ int red[256];
    int i = blockIdx.x * 256 + threadIdx.x;
    red[threadIdx.x] = (i < n) ? deg[i] : 0;
    __syncthreads();
#pragma unroll
    for (int off = 128; off > 0; off >>= 1) {
        if (threadIdx.x < off) red[threadIdx.x] += red[threadIdx.x + off];
        __syncthreads();
    }
    if (threadIdx.x == 0) bsum[blockIdx.x] = red[0];
}

__global__ void k_scan_bsum(int* __restrict__ bsum, int nb) {
    __shared__ int s[512];
    int t = threadIdx.x;
    int v = (t < nb) ? bsum[t] : 0;
    s[t] = v;
    __syncthreads();
#pragma unroll
    for (int off = 1; off < 512; off <<= 1) {
        int u = (t >= off) ? s[t - off] : 0;
        __syncthreads();
        s[t] += u;
        __syncthreads();
    }
    if (t < nb) bsum[t] = s[t] - v;
}

__global__ void k_scan_final(const int* __restrict__ deg, const int* __restrict__ bsum,
                             int* __restrict__ row_start, int n) {
    __shared__ int s[256];
    int i = blockIdx.x * 256 + threadIdx.x;
    int v = (i < n) ? deg[i] : 0;
    s[threadIdx.x] = v;
    __syncthreads();
#pragma unroll
    for (int off = 1; off < 256; off <<= 1) {
        int u = (threadIdx.x >= off) ? s[threadIdx.x - off] : 0;
        __syncthreads();
        s[threadIdx.x] += u;
        __syncthreads();
    }
    int excl = s[threadIdx.x] - v + bsum[blockIdx.x];
    if (i < n) row_start[i] = excl;
    if (i == n - 1) row_start[n] = excl + v;
}

// atomic-free placement, 4 edges/thread (4 independent row_start gathers in flight)
__global__ void k_place(const int* __restrict__ src, const int* __restrict__ dst,
                        const int* __restrict__ row_start, const int* __restrict__ epos,
                        int* __restrict__ csr_src, int E) {
    int e = (blockIdx.x * blockDim.x + threadIdx.x) * 4;
    if (e + 3 < E) {
        int4 d4 = *(const int4*)(dst + e);
        int4 p4 = *(const int4*)(epos + e);
        int4 s4 = *(const int4*)(src + e);
        int r0 = row_start[d4.x];
        int r1 = row_start[d4.y];
        int r2 = row_start[d4.z];
        int r3 = row_start[d4.w];
        csr_src[r0 + p4.x] = s4.x;
        csr_src[r1 + p4.y] = s4.y;
        csr_src[r2 + p4.z] = s4.z;
        csr_src[r3 + p4.w] = s4.w;
    } else {
        for (int k = e; k < E; ++k) csr_src[row_start[dst[k]] + epos[k]] = src[k];
    }
}

// ---------------- fp32 -> bf16 conversions -----------------------------------

__global__ void k_cvt_x(const float* __restrict__ src, unsigned short* __restrict__ dst, int n) {
    int i = (blockIdx.x * blockDim.x + threadIdx.x) * 4;
    if (i >= n) return;
    float4 v = *(const float4*)(src + i);
    uint2 o;
    o.x = pack2(v.x, v.y);
    o.y = pack2(v.z, v.w);
    *(uint2*)(dst + i) = o;
}

// wbuf layout: Wl1b[8192] | Wr1b[8192] | Wl2b[16384] | Wr2b[16384]
__global__ void k_cvt_w(const float* __restrict__ Wl1, const float* __restrict__ Wr1,
                        const float* __restrict__ Wl2, const float* __restrict__ Wr2,
                        unsigned short* __restrict__ wbuf) {
    int i = blockIdx.x * blockDim.x + threadIdx.x;
    if (i >= 49152) return;
    float v;
    if (i < 8192)       v = Wl1[i];
    else if (i < 16384) v = Wr1[i - 8192];
    else if (i < 32768) v = Wl2[i - 16384];
    else                v = Wr2[i - 32768];
    wbuf[i] = f2b(v);
}

// ---------------- mean aggregation (bf16 in/out, fp32 accumulate) ------------
// Wide-load edge-slot design + 2-deep unroll: two neighbor rows in flight
// per wave to hide L2/L3 latency.

#define ACC8(v)                                    \
    a[0] += __uint_as_float((v).x << 16);          \
    a[1] += __uint_as_float((v).x & 0xffff0000u);  \
    a[2] += __uint_as_float((v).y << 16);          \
    a[3] += __uint_as_float((v).y & 0xffff0000u);  \
    a[4] += __uint_as_float((v).z << 16);          \
    a[5] += __uint_as_float((v).z & 0xffff0000u);  \
    a[6] += __uint_as_float((v).w << 16);          \
    a[7] += __uint_as_float((v).w & 0xffff0000u);

// K=64: row = 128 B. 8 edge-slots x 8 lanes x uint4.
__global__ void k_gather1(const unsigned short* __restrict__ xb,
                          const int* __restrict__ row_start,
                          const int* __restrict__ csr_src,
                          unsigned short* __restrict__ agg, int n_nodes) {
    int tid = threadIdx.x;
    int node = blockIdx.x * 4 + (tid >> 6);
    if (node >= n_nodes) return;
    int lane = tid & 63;
    int grp = lane >> 3;       // edge slot 0..7
    int lp  = lane & 7;        // 8 lanes x 16B = 128 B row
    int s = row_start[node];
    int e = row_start[node + 1];
    float a[8];
#pragma unroll
    for (int q = 0; q < 8; ++q) a[q] = 0.f;
    int i = s + grp;
    for (; i + 8 < e; i += 16) {
        int u0 = csr_src[i];
        int u1 = csr_src[i + 8];
        uint4 v0 = *(const uint4*)(xb + (size_t)u0 * 64 + lp * 8);
        uint4 v1 = *(const uint4*)(xb + (size_t)u1 * 64 + lp * 8);
        ACC8(v0);
        ACC8(v1);
    }
    if (i < e) {
        int u0 = csr_src[i];
        uint4 v0 = *(const uint4*)(xb + (size_t)u0 * 64 + lp * 8);
        ACC8(v0);
    }
#pragma unroll
    for (int q = 0; q < 8; ++q) {
        a[q] += __shfl_xor(a[q], 8);
        a[q] += __shfl_xor(a[q], 16);
        a[q] += __shfl_xor(a[q], 32);
    }
    if (grp == 0) {
        int d = e - s;
        float scale = (d > 0) ? (1.f / (float)d) : 1.f;
        uint4 o;
        o.x = pack2(a[0] * scale, a[1] * scale);
        o.y = pack2(a[2] * scale, a[3] * scale);
        o.z = pack2(a[4] * scale, a[5] * scale);
        o.w = pack2(a[6] * scale, a[7] * scale);
        *(uint4*)(agg + (size_t)node * 64 + lp * 8) = o;
    }
}

// K=128: row = 256 B. 4 edge-slots x 16 lanes x uint4.
__global__ void k_gather2(const unsigned short* __restrict__ h1,
                          const int* __restrict__ row_start,
                          const int* __restrict__ csr_src,
                          unsigned short* __restrict__ agg, int n_nodes) {
    int tid = threadIdx.x;
    int node = blockIdx.x * 4 + (tid >> 6);
    if (node >= n_nodes) return;
    int lane = tid & 63;
    int grp = lane >> 4;       // edge slot 0..3
    int lp  = lane & 15;       // 16 lanes x 16B = 256 B row
    int s = row_start[node];
    int e = row_start[node + 1];
    float a[8];
#pragma unroll
    for (int q = 0; q < 8; ++q) a[q] = 0.f;
    int i = s + grp;
    for (; i + 4 < e; i += 8) {
        int u0 = csr_src[i];
        int u1 = csr_src[i + 4];
        uint4 v0 = *(const uint4*)(h1 + (size_t)u0 * 128 + lp * 8);
        uint4 v1 = *(const uint4*)(h1 + (size_t)u1 * 128 + lp * 8);
        ACC8(v0);
        ACC8(v1);
    }
    if (i < e) {
        int u0 = csr_src[i];
        uint4 v0 = *(const uint4*)(h1 + (size_t)u0 * 128 + lp * 8);
        ACC8(v0);
    }
#pragma unroll
    for (int q = 0; q < 8; ++q) {
        a[q] += __shfl_xor(a[q], 16);
        a[q] += __shfl_xor(a[q], 32);
    }
    if (grp == 0) {
        int d = e - s;
        float scale = (d > 0) ? (1.f / (float)d) : 1.f;
        uint4 o;
        o.x = pack2(a[0] * scale, a[1] * scale);
        o.y = pack2(a[2] * scale, a[3] * scale);
        o.z = pack2(a[4] * scale, a[5] * scale);
        o.w = pack2(a[6] * scale, a[7] * scale);
        *(uint4*)(agg + (size_t)node * 128 + lp * 8) = o;
    }
}

// ---------------- MFMA SAGE linear: out = relu(agg@Wl.T + bl + xin@Wr.T) ----

template <typename OutT>
__device__ inline void store_out(OutT* p, float v);
template <> __device__ inline void store_out<float>(float* p, float v) { *p = v; }
template <> __device__ inline void store_out<unsigned short>(unsigned short* p, float v) { *p = f2b(v); }

template <int K, typename OutT>
__global__ __launch_bounds__(256) void k_linear_mfma(
    const unsigned short* __restrict__ aggA, const unsigned short* __restrict__ xinA,
    const unsigned short* __restrict__ Wlb,  const float* __restrict__ bl,
    const unsigned short* __restrict__ Wrb,  OutT* __restrict__ out, int n_nodes) {
    constexpr int NCH = (2 * K) / 32;
    __shared__ __align__(16) short As[128 * 32];   // 8 KB

    int tid  = threadIdx.x;
    int lane = tid & 63;
    int wave = tid >> 6;
    int quad = lane >> 4;
    int lr   = lane & 15;
    int node0 = blockIdx.x * 128;

    floatx4 acc[8][2];
#pragma unroll
    for (int mi = 0; mi < 8; ++mi)
#pragma unroll
        for (int ni = 0; ni < 2; ++ni)
            acc[mi][ni] = (floatx4){0.f, 0.f, 0.f, 0.f};

    int srow = tid >> 2;
    int sslot = tid & 3;

#pragma unroll
    for (int c = 0; c < NCH; ++c) {
        const unsigned short* srcA;
        const unsigned short* srcW;
        int kb;
        if (c < K / 32) { srcA = aggA; srcW = Wlb; kb = c * 32; }
        else            { srcA = xinA; srcW = Wrb; kb = c * 32 - K; }

        __syncthreads();
        {
            int n1 = node0 + srow;       if (n1 >= n_nodes) n1 = n_nodes - 1;
            int n2 = node0 + srow + 64;  if (n2 >= n_nodes) n2 = n_nodes - 1;
            uint4 v1 = *(const uint4*)(srcA + (size_t)n1 * K + kb + sslot * 8);
            uint4 v2 = *(const uint4*)(srcA + (size_t)n2 * K + kb + sslot * 8);
            *(uint4*)(&As[srow * 32 + sslot * 8]) = v1;
            *(uint4*)(&As[(srow + 64) * 32 + sslot * 8]) = v2;
        }
        __syncthreads();

        short8_t bfrag[2];
#pragma unroll
        for (int ni = 0; ni < 2; ++ni) {
            int j = wave * 32 + ni * 16 + lr;
            bfrag[ni] = *(const short8_t*)(srcW + (size_t)j * K + kb + quad * 8);
        }
#pragma unroll
        for (int mi = 0; mi < 8; ++mi) {
            short8_t af = *(const short8_t*)(&As[(mi * 16 + lr) * 32 + quad * 8]);
            acc[mi][0] = __builtin_amdgcn_mfma_f32_16x16x32_bf16(af, bfrag[0], acc[mi][0], 0, 0, 0);
            acc[mi][1] = __builtin_amdgcn_mfma_f32_16x16x32_bf16(af, bfrag[1], acc[mi][1], 0, 0, 0);
        }
    }

    float b0 = bl[wave * 32 + lr];
    float b1 = bl[wave * 32 + 16 + lr];
    int j0 = wave * 32 + lr;
#pragma unroll
    for (int mi = 0; mi < 8; ++mi) {
#pragma unroll
        for (int r = 0; r < 4; ++r) {
            int node = node0 + mi * 16 + quad * 4 + r;
            if (node < n_nodes) {
                float v0 = fmaxf(acc[mi][0][r] + b0, 0.f);
                float v1 = fmaxf(acc[mi][1][r] + b1, 0.f);
                store_out(out + (size_t)node * 128 + j0, v0);
                store_out(out + (size_t)node * 128 + j0 + 16, v1);
            }
        }
    }
}

// ---------------- pooling: batch is SORTED -> segmented reduction ------------

__global__ void k_graph_bounds(const int* __restrict__ batch, int* __restrict__ gstart,
                               int N, int G) {
    int g = blockIdx.x * blockDim.x + threadIdx.x;
    if (g > G) return;
    if (g == G) { gstart[G] = N; return; }
    int lo = 0, hi = N;
    while (lo < hi) {
        int mid = (lo + hi) >> 1;
        if (batch[mid] < g) lo = mid + 1; else hi = mid;
    }
    gstart[g] = lo;
}

// h2 in bf16: lane reads one uint (2 channels)
__global__ __launch_bounds__(256) void k_pool_seg(const unsigned short* __restrict__ h2b,
                                                  const int* __restrict__ gstart,
                                                  float* __restrict__ pooled,
                                                  float* __restrict__ cnt) {
    int g = blockIdx.x;
    int s = gstart[g], e = gstart[g + 1];
    int lane = threadIdx.x & 63;
    int wave = threadIdx.x >> 6;
    float ax = 0.f, ay = 0.f;
    for (int n = s + wave; n < e; n += 4) {
        uint v = ((const uint*)(h2b + (size_t)n * 128))[lane];
        ax += __uint_as_float(v << 16);
        ay += __uint_as_float(v & 0xffff0000u);
    }
    __shared__ float2 red[4][64];
    red[wave][lane] = make_float2(ax, ay);
    __syncthreads();
    if (wave == 0) {
        float2 a = red[0][lane], b = red[1][lane], c = red[2][lane], d = red[3][lane];
        float2 o;
        o.x = a.x + b.x + c.x + d.x;
        o.y = a.y + b.y + c.y + d.y;
        ((float2*)(pooled + g * 128))[lane] = o;
        if (lane == 0) cnt[g] = (float)(e - s);
    }
}

// ---------------- head: mean, linear [2x128], log_softmax -------------------

__global__ void k_head(const float* __restrict__ pooled, const float* __restrict__ cnt,
                       const float* __restrict__ Wout, const float* __restrict__ bout,
                       float* __restrict__ out) {
    int g = blockIdx.x;
    int lane = threadIdx.x;
    float c = cnt[g];
    float inv = (c > 0.f) ? (1.f / c) : 1.f;
    float2 p  = ((const float2*)(pooled + g * 128))[lane];
    p.x *= inv; p.y *= inv;
    float2 w0 = ((const float2*)(Wout))[lane];
    float2 w1 = ((const float2*)(Wout + 128))[lane];
    float d0 = p.x * w0.x + p.y * w0.y;
    float d1 = p.x * w1.x + p.y * w1.y;
#pragma unroll
    for (int m = 32; m > 0; m >>= 1) {
        d0 += __shfl_xor(d0, m);
        d1 += __shfl_xor(d1, m);
    }
    if (lane == 0) {
        float l0 = d0 + bout[0];
        float l1 = d1 + bout[1];
        float mx = fmaxf(l0, l1);
        float lse = mx + logf(expf(l0 - mx) + expf(l1 - mx));
        out[g * 2 + 0] = l0 - lse;
        out[g * 2 + 1] = l1 - lse;
    }
}

// ---------------- launch -----------------------------------------------------

static inline size_t alignUp(size_t x, size_t a) { return (x + a - 1) & ~(a - 1); }

extern "C" void kernel_launch(void* const* d_in, const int* in_sizes, int n_in,
                              void* d_out, int out_size, void* d_ws, size_t ws_size,
                              hipStream_t stream) {
    const float* x    = (const float*)d_in[0];
    const int*   ei   = (const int*)d_in[1];
    const int*   batch= (const int*)d_in[2];
    const float* Wl1  = (const float*)d_in[3];
    const float* bl1  = (const float*)d_in[4];
    const float* Wr1  = (const float*)d_in[5];
    const float* Wl2  = (const float*)d_in[6];
    const float* bl2  = (const float*)d_in[7];
    const float* Wr2  = (const float*)d_in[8];
    const float* Wout = (const float*)d_in[9];
    const float* bout = (const float*)d_in[10];
    float* out = (float*)d_out;

    const int N = in_sizes[0] / 64;   // 100000
    const int E = in_sizes[1] / 2;    // 1000000
    const int G = out_size / 2;       // 256

    const int* src = ei;
    const int* dst = ei + E;

    const int nScanBlocks = (N + 255) / 256;

    // workspace layout
    char* ws = (char*)d_ws;
    size_t off = 0;
    int*   deg       = (int*)(ws + off); off = alignUp(off + (size_t)N * 4, 256);
    int*   row_start = (int*)(ws + off); off = alignUp(off + (size_t)(N + 1) * 4, 256);
    int*   epos      = (int*)(ws + off); off = alignUp(off + (size_t)E * 4, 256);
    int*   csr_src   = (int*)(ws + off); off = alignUp(off + (size_t)E * 4, 256);
    int*   bsum      = (int*)(ws + off); off = alignUp(off + (size_t)512 * 4, 256);
    int*   gstart    = (int*)(ws + off); off = alignUp(off + (size_t)(G + 1) * 4, 256);
    unsigned short* xb   = (unsigned short*)(ws + off); off = alignUp(off + (size_t)N * 64 * 2, 256);
    unsigned short* wbuf = (unsigned short*)(ws + off); off = alignUp(off + (size_t)49152 * 2, 256);
    unsigned short* agg1 = (unsigned short*)(ws + off); off = alignUp(off + (size_t)N * 64 * 2, 256);
    unsigned short* h1   = (unsigned short*)(ws + off); off = alignUp(off + (size_t)N * 128 * 2, 256);
    unsigned short* agg2 = (unsigned short*)(ws + off); off = alignUp(off + (size_t)N * 128 * 2, 256);
    unsigned short* h2b  = (unsigned short*)(ws + off); off = alignUp(off + (size_t)N * 128 * 2, 256);
    float* pooled    = (float*)(ws + off); off = alignUp(off + (size_t)G * 128 * 4, 256);
    float* cnt       = (float*)(ws + off); off = alignUp(off + (size_t)G * 4, 256);
    (void)ws_size;

    unsigned short* Wl1b = wbuf;
    unsigned short* Wr1b = wbuf + 8192;
    unsigned short* Wl2b = wbuf + 16384;
    unsigned short* Wr2b = wbuf + 32768;

    // zero deg only
    hipMemsetAsync(deg, 0, (size_t)N * 4, stream);

    // conversions
    k_cvt_x<<<(N * 64 / 4 + 255) / 256, 256, 0, stream>>>(x, xb, N * 64);
    k_cvt_w<<<192, 256, 0, stream>>>(Wl1, Wr1, Wl2, Wr2, wbuf);

    // CSR build (single atomic pass + scan + atomic-free placement)
    k_count_pos<<<(E / 4 + 255) / 256, 256, 0, stream>>>(dst, deg, epos, E);
    k_block_sum<<<nScanBlocks, 256, 0, stream>>>(deg, bsum, N);
    k_scan_bsum<<<1, 512, 0, stream>>>(bsum, nScanBlocks);
    k_scan_final<<<nScanBlocks, 256, 0, stream>>>(deg, bsum, row_start, N);
    k_place<<<(E / 4 + 255) / 256, 256, 0, stream>>>(src, dst, row_start, epos, csr_src, E);

    // graph segment bounds from sorted batch
    k_graph_bounds<<<2, 256, 0, stream>>>(batch, gstart, N, G);

    // layer 1
    k_gather1<<<(N + 3) / 4, 256, 0, stream>>>(xb, row_start, csr_src, agg1, N);
    k_linear_mfma<64, unsigned short><<<(N + 127) / 128, 256, 0, stream>>>(
        agg1, xb, Wl1b, bl1, Wr1b, h1, N);

    // layer 2 (h2 in bf16)
    k_gather2<<<(N + 3) / 4, 256, 0, stream>>>(h1, row_start, csr_src, agg2, N);
    k_linear_mfma<128, unsigned short><<<(N + 127) / 128, 256, 0, stream>>>(
        agg2, h1, Wl2b, bl2, Wr2b, h2b, N);

    // pool + head
    k_pool_seg<<<G, 256, 0, stream>>>(h2b, gstart, pooled, cnt);
    k_head<<<G, 64, 0, stream>>>(pooled, cnt, Wout, bout, out);
}

// Round 8
// 331.733 us; speedup vs baseline: 3.2986x; 1.0101x over previous
//
#include <hip/hip_runtime.h>
#include <hip/hip_bf16.h>
#include <math.h>

typedef short short8_t __attribute__((ext_vector_type(8)));
typedef float floatx4  __attribute__((ext_vector_type(4)));
typedef float floatx2  __attribute__((ext_vector_type(2)));
typedef unsigned int uint;

// ---------------- bf16 helpers (RNE) ----------------------------------------

__device__ inline unsigned short f2b(float f) {
    uint u = __float_as_uint(f);
    u += 0x7fff + ((u >> 16) & 1);
    return (unsigned short)(u >> 16);
}
__device__ inline uint pack2(float a, float b) {
    return (uint)f2b(a) | ((uint)f2b(b) << 16);
}
__device__ inline float blo(uint v) { return __uint_as_float(v << 16); }
__device__ inline float bhi(uint v) { return __uint_as_float(v & 0xffff0000u); }

// ---------------- fp8 (e4m3) helpers: HW pack converters ---------------------
// encode 4 floats into one uint (bytes 0..3 = f0..f3)
__device__ inline uint enc4_fp8(float f0, float f1, float f2, float f3) {
    uint v = __builtin_amdgcn_cvt_pk_fp8_f32(f0, f1, 0, false);
    v = __builtin_amdgcn_cvt_pk_fp8_f32(f2, f3, v, true);
    return v;
}

// ---------------- CSR build ---------------------------------------------------

__global__ void k_count_pos(const int* __restrict__ dst, int* __restrict__ deg,
                            int* __restrict__ epos, int E) {
    int e = (blockIdx.x * blockDim.x + threadIdx.x) * 4;
    if (e + 3 < E) {
        int4 d4 = *(const int4*)(dst + e);
        int4 p;
        p.x = atomicAdd(&deg[d4.x], 1);
        p.y = atomicAdd(&deg[d4.y], 1);
        p.z = atomicAdd(&deg[d4.z], 1);
        p.w = atomicAdd(&deg[d4.w], 1);
        *(int4*)(epos + e) = p;
    } else {
        for (int k = e; k < E; ++k) epos[k] = atomicAdd(&deg[dst[k]], 1);
    }
}

__global__ void k_block_sum(const int* __restrict__ deg, int* __restrict__ bsum, int n) {
    __shared__ int red[256];
    int i = blockIdx.x * 256 + threadIdx.x;
    red[threadIdx.x] = (i < n) ? deg[i] : 0;
    __syncthreads();
#pragma unroll
    for (int off = 128; off > 0; off >>= 1) {
        if (threadIdx.x < off) red[threadIdx.x] += red[threadIdx.x + off];
        __syncthreads();
    }
    if (threadIdx.x == 0) bsum[blockIdx.x] = red[0];
}

__global__ void k_scan_bsum(int* __restrict__ bsum, int nb) {
    __shared__ int s[512];
    int t = threadIdx.x;
    int v = (t < nb) ? bsum[t] : 0;
    s[t] = v;
    __syncthreads();
#pragma unroll
    for (int off = 1; off < 512; off <<= 1) {
        int u = (t >= off) ? s[t - off] : 0;
        __syncthreads();
        s[t] += u;
        __syncthreads();
    }
    if (t < nb) bsum[t] = s[t] - v;
}

__global__ void k_scan_final(const int* __restrict__ deg, const int* __restrict__ bsum,
                             int* __restrict__ row_start, int n) {
    __shared__ int s[256];
    int i = blockIdx.x * 256 + threadIdx.x;
    int v = (i < n) ? deg[i] : 0;
    s[threadIdx.x] = v;
    __syncthreads();
#pragma unroll
    for (int off = 1; off < 256; off <<= 1) {
        int u = (threadIdx.x >= off) ? s[threadIdx.x - off] : 0;
        __syncthreads();
        s[threadIdx.x] += u;
        __syncthreads();
    }
    int excl = s[threadIdx.x] - v + bsum[blockIdx.x];
    if (i < n) row_start[i] = excl;
    if (i == n - 1) row_start[n] = excl + v;
}

__global__ void k_place(const int* __restrict__ src, const int* __restrict__ dst,
                        const int* __restrict__ row_start, const int* __restrict__ epos,
                        int* __restrict__ csr_src, int E) {
    int e = (blockIdx.x * blockDim.x + threadIdx.x) * 4;
    if (e + 3 < E) {
        int4 d4 = *(const int4*)(dst + e);
        int4 p4 = *(const int4*)(epos + e);
        int4 s4 = *(const int4*)(src + e);
        int r0 = row_start[d4.x];
        int r1 = row_start[d4.y];
        int r2 = row_start[d4.z];
        int r3 = row_start[d4.w];
        csr_src[r0 + p4.x] = s4.x;
        csr_src[r1 + p4.y] = s4.y;
        csr_src[r2 + p4.z] = s4.z;
        csr_src[r3 + p4.w] = s4.w;
    } else {
        for (int k = e; k < E; ++k) csr_src[row_start[dst[k]] + epos[k]] = src[k];
    }
}

// ---------------- conversions -------------------------------------------------

// x fp32 -> xb (bf16) and xf8 (fp8), 8 elements/thread
__global__ void k_cvt_x(const float* __restrict__ src, unsigned short* __restrict__ xb,
                        unsigned char* __restrict__ xf8, int n) {
    int i = (blockIdx.x * blockDim.x + threadIdx.x) * 8;
    if (i >= n) return;
    float4 v0 = *(const float4*)(src + i);
    float4 v1 = *(const float4*)(src + i + 4);
    uint4 ob;
    ob.x = pack2(v0.x, v0.y);
    ob.y = pack2(v0.z, v0.w);
    ob.z = pack2(v1.x, v1.y);
    ob.w = pack2(v1.z, v1.w);
    *(uint4*)(xb + i) = ob;
    uint2 of;
    of.x = enc4_fp8(v0.x, v0.y, v0.z, v0.w);
    of.y = enc4_fp8(v1.x, v1.y, v1.z, v1.w);
    *(uint2*)(xf8 + i) = of;
}

// h1 bf16 -> fp8, 8 elements/thread
__global__ void k_cvt_h1(const unsigned short* __restrict__ h1,
                         unsigned char* __restrict__ h1f8, int n) {
    int i = (blockIdx.x * blockDim.x + threadIdx.x) * 8;
    if (i >= n) return;
    uint4 v = *(const uint4*)(h1 + i);
    uint2 o;
    o.x = enc4_fp8(blo(v.x), bhi(v.x), blo(v.y), bhi(v.y));
    o.y = enc4_fp8(blo(v.z), bhi(v.z), blo(v.w), bhi(v.w));
    *(uint2*)(h1f8 + i) = o;
}

// wbuf layout: Wl1b[8192] | Wr1b[8192] | Wl2b[16384] | Wr2b[16384]
__global__ void k_cvt_w(const float* __restrict__ Wl1, const float* __restrict__ Wr1,
                        const float* __restrict__ Wl2, const float* __restrict__ Wr2,
                        unsigned short* __restrict__ wbuf) {
    int i = blockIdx.x * blockDim.x + threadIdx.x;
    if (i >= 49152) return;
    float v;
    if (i < 8192)       v = Wl1[i];
    else if (i < 16384) v = Wr1[i - 8192];
    else if (i < 32768) v = Wl2[i - 16384];
    else                v = Wr2[i - 32768];
    wbuf[i] = f2b(v);
}

// ---------------- mean aggregation (fp8 in, bf16 out, fp32 accumulate) -------
// decode uint2 (8 fp8) and accumulate into a[0..7]; ext-vector result needs
// [] indexing (no .x/.y members on clang ext_vector float2)
#define ACCF8(v)                                                        \
    { floatx2 f = __builtin_amdgcn_cvt_pk_f32_fp8((v).x, false);        \
      a[0] += f[0]; a[1] += f[1];                                       \
      f = __builtin_amdgcn_cvt_pk_f32_fp8((v).x, true);                 \
      a[2] += f[0]; a[3] += f[1];                                       \
      f = __builtin_amdgcn_cvt_pk_f32_fp8((v).y, false);                \
      a[4] += f[0]; a[5] += f[1];                                       \
      f = __builtin_amdgcn_cvt_pk_f32_fp8((v).y, true);                 \
      a[6] += f[0]; a[7] += f[1]; }

// K=64: row = 64 B fp8. 8 edge-slots x 8 lanes x uint2; 2-deep unroll
// -> 16 rows in flight per wave.
__global__ void k_gather1(const unsigned char* __restrict__ xf8,
                          const int* __restrict__ row_start,
                          const int* __restrict__ csr_src,
                          unsigned short* __restrict__ agg, int n_nodes) {
    int tid = threadIdx.x;
    int node = blockIdx.x * 4 + (tid >> 6);
    if (node >= n_nodes) return;
    int lane = tid & 63;
    int grp = lane >> 3;       // edge slot 0..7
    int lp  = lane & 7;        // 8 lanes x 8B = 64 B row
    int s = row_start[node];
    int e = row_start[node + 1];
    float a[8];
#pragma unroll
    for (int q = 0; q < 8; ++q) a[q] = 0.f;
    int i = s + grp;
    for (; i + 8 < e; i += 16) {
        int u0 = csr_src[i];
        int u1 = csr_src[i + 8];
        uint2 v0 = *(const uint2*)(xf8 + (size_t)u0 * 64 + lp * 8);
        uint2 v1 = *(const uint2*)(xf8 + (size_t)u1 * 64 + lp * 8);
        ACCF8(v0);
        ACCF8(v1);
    }
    if (i < e) {
        int u0 = csr_src[i];
        uint2 v0 = *(const uint2*)(xf8 + (size_t)u0 * 64 + lp * 8);
        ACCF8(v0);
    }
#pragma unroll
    for (int q = 0; q < 8; ++q) {
        a[q] += __shfl_xor(a[q], 8);
        a[q] += __shfl_xor(a[q], 16);
        a[q] += __shfl_xor(a[q], 32);
    }
    if (grp == 0) {
        int d = e - s;
        float scale = (d > 0) ? (1.f / (float)d) : 1.f;
        uint4 o;
        o.x = pack2(a[0] * scale, a[1] * scale);
        o.y = pack2(a[2] * scale, a[3] * scale);
        o.z = pack2(a[4] * scale, a[5] * scale);
        o.w = pack2(a[6] * scale, a[7] * scale);
        *(uint4*)(agg + (size_t)node * 64 + lp * 8) = o;
    }
}

// K=128: row = 128 B fp8. 4 edge-slots x 16 lanes x uint2; 2-deep unroll
// -> 8 rows in flight per wave.
__global__ void k_gather2(const unsigned char* __restrict__ h1f8,
                          const int* __restrict__ row_start,
                          const int* __restrict__ csr_src,
                          unsigned short* __restrict__ agg, int n_nodes) {
    int tid = threadIdx.x;
    int node = blockIdx.x * 4 + (tid >> 6);
    if (node >= n_nodes) return;
    int lane = tid & 63;
    int grp = lane >> 4;       // edge slot 0..3
    int lp  = lane & 15;       // 16 lanes x 8B = 128 B row
    int s = row_start[node];
    int e = row_start[node + 1];
    float a[8];
#pragma unroll
    for (int q = 0; q < 8; ++q) a[q] = 0.f;
    int i = s + grp;
    for (; i + 4 < e; i += 8) {
        int u0 = csr_src[i];
        int u1 = csr_src[i + 4];
        uint2 v0 = *(const uint2*)(h1f8 + (size_t)u0 * 128 + lp * 8);
        uint2 v1 = *(const uint2*)(h1f8 + (size_t)u1 * 128 + lp * 8);
        ACCF8(v0);
        ACCF8(v1);
    }
    if (i < e) {
        int u0 = csr_src[i];
        uint2 v0 = *(const uint2*)(h1f8 + (size_t)u0 * 128 + lp * 8);
        ACCF8(v0);
    }
#pragma unroll
    for (int q = 0; q < 8; ++q) {
        a[q] += __shfl_xor(a[q], 16);
        a[q] += __shfl_xor(a[q], 32);
    }
    if (grp == 0) {
        int d = e - s;
        float scale = (d > 0) ? (1.f / (float)d) : 1.f;
        uint4 o;
        o.x = pack2(a[0] * scale, a[1] * scale);
        o.y = pack2(a[2] * scale, a[3] * scale);
        o.z = pack2(a[4] * scale, a[5] * scale);
        o.w = pack2(a[6] * scale, a[7] * scale);
        *(uint4*)(agg + (size_t)node * 128 + lp * 8) = o;
    }
}

// ---------------- MFMA SAGE linear: out = relu(agg@Wl.T + bl + xin@Wr.T) ----

template <typename OutT>
__device__ inline void store_out(OutT* p, float v);
template <> __device__ inline void store_out<float>(float* p, float v) { *p = v; }
template <> __device__ inline void store_out<unsigned short>(unsigned short* p, float v) { *p = f2b(v); }

template <int K, typename OutT>
__global__ __launch_bounds__(256) void k_linear_mfma(
    const unsigned short* __restrict__ aggA, const unsigned short* __restrict__ xinA,
    const unsigned short* __restrict__ Wlb,  const float* __restrict__ bl,
    const unsigned short* __restrict__ Wrb,  OutT* __restrict__ out, int n_nodes) {
    constexpr int NCH = (2 * K) / 32;
    __shared__ __align__(16) short As[128 * 32];   // 8 KB

    int tid  = threadIdx.x;
    int lane = tid & 63;
    int wave = tid >> 6;
    int quad = lane >> 4;
    int lr   = lane & 15;
    int node0 = blockIdx.x * 128;

    floatx4 acc[8][2];
#pragma unroll
    for (int mi = 0; mi < 8; ++mi)
#pragma unroll
        for (int ni = 0; ni < 2; ++ni)
            acc[mi][ni] = (floatx4){0.f, 0.f, 0.f, 0.f};

    int srow = tid >> 2;
    int sslot = tid & 3;

#pragma unroll
    for (int c = 0; c < NCH; ++c) {
        const unsigned short* srcA;
        const unsigned short* srcW;
        int kb;
        if (c < K / 32) { srcA = aggA; srcW = Wlb; kb = c * 32; }
        else            { srcA = xinA; srcW = Wrb; kb = c * 32 - K; }

        __syncthreads();
        {
            int n1 = node0 + srow;       if (n1 >= n_nodes) n1 = n_nodes - 1;
            int n2 = node0 + srow + 64;  if (n2 >= n_nodes) n2 = n_nodes - 1;
            uint4 v1 = *(const uint4*)(srcA + (size_t)n1 * K + kb + sslot * 8);
            uint4 v2 = *(const uint4*)(srcA + (size_t)n2 * K + kb + sslot * 8);
            *(uint4*)(&As[srow * 32 + sslot * 8]) = v1;
            *(uint4*)(&As[(srow + 64) * 32 + sslot * 8]) = v2;
        }
        __syncthreads();

        short8_t bfrag[2];
#pragma unroll
        for (int ni = 0; ni < 2; ++ni) {
            int j = wave * 32 + ni * 16 + lr;
            bfrag[ni] = *(const short8_t*)(srcW + (size_t)j * K + kb + quad * 8);
        }
#pragma unroll
        for (int mi = 0; mi < 8; ++mi) {
            short8_t af = *(const short8_t*)(&As[(mi * 16 + lr) * 32 + quad * 8]);
            acc[mi][0] = __builtin_amdgcn_mfma_f32_16x16x32_bf16(af, bfrag[0], acc[mi][0], 0, 0, 0);
            acc[mi][1] = __builtin_amdgcn_mfma_f32_16x16x32_bf16(af, bfrag[1], acc[mi][1], 0, 0, 0);
        }
    }

    float b0 = bl[wave * 32 + lr];
    float b1 = bl[wave * 32 + 16 + lr];
    int j0 = wave * 32 + lr;
#pragma unroll
    for (int mi = 0; mi < 8; ++mi) {
#pragma unroll
        for (int r = 0; r < 4; ++r) {
            int node = node0 + mi * 16 + quad * 4 + r;
            if (node < n_nodes) {
                float v0 = fmaxf(acc[mi][0][r] + b0, 0.f);
                float v1 = fmaxf(acc[mi][1][r] + b1, 0.f);
                store_out(out + (size_t)node * 128 + j0, v0);
                store_out(out + (size_t)node * 128 + j0 + 16, v1);
            }
        }
    }
}

// ---------------- pooling: batch is SORTED -> segmented reduction ------------

__global__ void k_graph_bounds(const int* __restrict__ batch, int* __restrict__ gstart,
                               int N, int G) {
    int g = blockIdx.x * blockDim.x + threadIdx.x;
    if (g > G) return;
    if (g == G) { gstart[G] = N; return; }
    int lo = 0, hi = N;
    while (lo < hi) {
        int mid = (lo + hi) >> 1;
        if (batch[mid] < g) lo = mid + 1; else hi = mid;
    }
    gstart[g] = lo;
}

__global__ __launch_bounds__(256) void k_pool_seg(const unsigned short* __restrict__ h2b,
                                                  const int* __restrict__ gstart,
                                                  float* __restrict__ pooled,
                                                  float* __restrict__ cnt) {
    int g = blockIdx.x;
    int s = gstart[g], e = gstart[g + 1];
    int lane = threadIdx.x & 63;
    int wave = threadIdx.x >> 6;
    float ax = 0.f, ay = 0.f;
    for (int n = s + wave; n < e; n += 4) {
        uint v = ((const uint*)(h2b + (size_t)n * 128))[lane];
        ax += blo(v);
        ay += bhi(v);
    }
    __shared__ float2 red[4][64];
    red[wave][lane] = make_float2(ax, ay);
    __syncthreads();
    if (wave == 0) {
        float2 a = red[0][lane], b = red[1][lane], c = red[2][lane], d = red[3][lane];
        float2 o;
        o.x = a.x + b.x + c.x + d.x;
        o.y = a.y + b.y + c.y + d.y;
        ((float2*)(pooled + g * 128))[lane] = o;
        if (lane == 0) cnt[g] = (float)(e - s);
    }
}

// ---------------- head: mean, linear [2x128], log_softmax -------------------

__global__ void k_head(const float* __restrict__ pooled, const float* __restrict__ cnt,
                       const float* __restrict__ Wout, const float* __restrict__ bout,
                       float* __restrict__ out) {
    int g = blockIdx.x;
    int lane = threadIdx.x;
    float c = cnt[g];
    float inv = (c > 0.f) ? (1.f / c) : 1.f;
    float2 p  = ((const float2*)(pooled + g * 128))[lane];
    p.x *= inv; p.y *= inv;
    float2 w0 = ((const float2*)(Wout))[lane];
    float2 w1 = ((const float2*)(Wout + 128))[lane];
    float d0 = p.x * w0.x + p.y * w0.y;
    float d1 = p.x * w1.x + p.y * w1.y;
#pragma unroll
    for (int m = 32; m > 0; m >>= 1) {
        d0 += __shfl_xor(d0, m);
        d1 += __shfl_xor(d1, m);
    }
    if (lane == 0) {
        float l0 = d0 + bout[0];
        float l1 = d1 + bout[1];
        float mx = fmaxf(l0, l1);
        float lse = mx + logf(expf(l0 - mx) + expf(l1 - mx));
        out[g * 2 + 0] = l0 - lse;
        out[g * 2 + 1] = l1 - lse;
    }
}

// ---------------- launch -----------------------------------------------------

static inline size_t alignUp(size_t x, size_t a) { return (x + a - 1) & ~(a - 1); }

extern "C" void kernel_launch(void* const* d_in, const int* in_sizes, int n_in,
                              void* d_out, int out_size, void* d_ws, size_t ws_size,
                              hipStream_t stream) {
    const float* x    = (const float*)d_in[0];
    const int*   ei   = (const int*)d_in[1];
    const int*   batch= (const int*)d_in[2];
    const float* Wl1  = (const float*)d_in[3];
    const float* bl1  = (const float*)d_in[4];
    const float* Wr1  = (const float*)d_in[5];
    const float* Wl2  = (const float*)d_in[6];
    const float* bl2  = (const float*)d_in[7];
    const float* Wr2  = (const float*)d_in[8];
    const float* Wout = (const float*)d_in[9];
    const float* bout = (const float*)d_in[10];
    float* out = (float*)d_out;

    const int N = in_sizes[0] / 64;   // 100000
    const int E = in_sizes[1] / 2;    // 1000000
    const int G = out_size / 2;       // 256

    const int* src = ei;
    const int* dst = ei + E;

    const int nScanBlocks = (N + 255) / 256;

    // workspace layout
    char* ws = (char*)d_ws;
    size_t off = 0;
    int*   deg       = (int*)(ws + off); off = alignUp(off + (size_t)N * 4, 256);
    int*   row_start = (int*)(ws + off); off = alignUp(off + (size_t)(N + 1) * 4, 256);
    int*   epos      = (int*)(ws + off); off = alignUp(off + (size_t)E * 4, 256);
    int*   csr_src   = (int*)(ws + off); off = alignUp(off + (size_t)E * 4, 256);
    int*   bsum      = (int*)(ws + off); off = alignUp(off + (size_t)512 * 4, 256);
    int*   gstart    = (int*)(ws + off); off = alignUp(off + (size_t)(G + 1) * 4, 256);
    unsigned short* xb   = (unsigned short*)(ws + off); off = alignUp(off + (size_t)N * 64 * 2, 256);
    unsigned char*  xf8  = (unsigned char*)(ws + off);  off = alignUp(off + (size_t)N * 64, 256);
    unsigned short* wbuf = (unsigned short*)(ws + off); off = alignUp(off + (size_t)49152 * 2, 256);
    unsigned short* agg1 = (unsigned short*)(ws + off); off = alignUp(off + (size_t)N * 64 * 2, 256);
    unsigned short* h1   = (unsigned short*)(ws + off); off = alignUp(off + (size_t)N * 128 * 2, 256);
    unsigned char*  h1f8 = (unsigned char*)(ws + off);  off = alignUp(off + (size_t)N * 128, 256);
    unsigned short* agg2 = (unsigned short*)(ws + off); off = alignUp(off + (size_t)N * 128 * 2, 256);
    unsigned short* h2b  = (unsigned short*)(ws + off); off = alignUp(off + (size_t)N * 128 * 2, 256);
    float* pooled    = (float*)(ws + off); off = alignUp(off + (size_t)G * 128 * 4, 256);
    float* cnt       = (float*)(ws + off); off = alignUp(off + (size_t)G * 4, 256);
    (void)ws_size;

    unsigned short* Wl1b = wbuf;
    unsigned short* Wr1b = wbuf + 8192;
    unsigned short* Wl2b = wbuf + 16384;
    unsigned short* Wr2b = wbuf + 32768;

    // zero deg only
    hipMemsetAsync(deg, 0, (size_t)N * 4, stream);

    // conversions
    k_cvt_x<<<(N * 64 / 8 + 255) / 256, 256, 0, stream>>>(x, xb, xf8, N * 64);
    k_cvt_w<<<192, 256, 0, stream>>>(Wl1, Wr1, Wl2, Wr2, wbuf);

    // CSR build (single atomic pass + scan + atomic-free placement)
    k_count_pos<<<(E / 4 + 255) / 256, 256, 0, stream>>>(dst, deg, epos, E);
    k_block_sum<<<nScanBlocks, 256, 0, stream>>>(deg, bsum, N);
    k_scan_bsum<<<1, 512, 0, stream>>>(bsum, nScanBlocks);
    k_scan_final<<<nScanBlocks, 256, 0, stream>>>(deg, bsum, row_start, N);
    k_place<<<(E / 4 + 255) / 256, 256, 0, stream>>>(src, dst, row_start, epos, csr_src, E);

    // graph segment bounds from sorted batch
    k_graph_bounds<<<2, 256, 0, stream>>>(batch, gstart, N, G);

    // layer 1: gather from fp8 x, linear in bf16 MFMA
    k_gather1<<<(N + 3) / 4, 256, 0, stream>>>(xf8, row_start, csr_src, agg1, N);
    k_linear_mfma<64, unsigned short><<<(N + 127) / 128, 256, 0, stream>>>(
        agg1, xb, Wl1b, bl1, Wr1b, h1, N);

    // h1 -> fp8 copy for the layer-2 gather
    k_cvt_h1<<<(N * 128 / 8 + 255) / 256, 256, 0, stream>>>(h1, h1f8, N * 128);

    // layer 2
    k_gather2<<<(N + 3) / 4, 256, 0, stream>>>(h1f8, row_start, csr_src, agg2, N);
    k_linear_mfma<128, unsigned short><<<(N + 127) / 128, 256, 0, stream>>>(
        agg2, h1, Wl2b, bl2, Wr2b, h2b, N);

    // pool + head
    k_pool_seg<<<G, 256, 0, stream>>>(h2b, gstart, pooled, cnt);
    k_head<<<G, 64, 0, stream>>>(pooled, cnt, Wout, bout, out);
}